// Round 1
// baseline (1929.881 us; speedup 1.0000x reference)
//
#include <hip/hip_runtime.h>
#include <hip/hip_fp8.h>
#include <cstdint>
#include <cstddef>

// Problem dims (TemporalLSTM_77455440216810)
#define IDIM 128   // INPUT_DIM
#define HS   256   // HIDDEN
#define SEQL 512   // SEQ
#define TOUT 24    // OUT (scan steps)
#define TMP  64    // TEMP
#define NB   512   // B
#define G4   1024  // 4*HS

typedef unsigned short u16;
typedef unsigned int   u32;
typedef __attribute__((ext_vector_type(4))) float f32x4;   // MFMA C/D frag

// ---- LDS layout (bytes). ONE batch element per WG. Total 81000 <= 81920
// ---- so TWO WGs (2048 threads) co-reside per CU -> 100% occupancy.
#define OFF_HFRAG 0        // 65536: 512x128 fp8 MFMA-A frags
#define OFF_GATEP 65536    // 8192: gate partials u32[4][512] (bf16 pairs)
                           //       UNION Wa fp8 B-frags (8192) -- disjoint phases
#define OFF_E     73728    // 2048: e[512] f32
#define OFF_CUAP  75776    // 2048: cua partials [8][64] f32
                           //       UNION ctx partials [4][128] f32 -- disjoint
#define OFF_H     77824    // 1024: h[256] f32
#define OFF_C     78848    // 1024: c[256] f32
#define OFF_CTX   79872    // 512:  ctx[128] f32
#define OFF_CUABA 80384    // 256:  cua+ba [64] f32
#define OFF_VA    80640    // 256:  Va_t [64] f32
#define OFF_RED   80896    // 96:   reduction scratch [24] f32
#define OFF_Y     80992    // 4
#define OFF_INVD  80996    // 4
#define SMEM_BYTES 81000

__device__ __forceinline__ u16 f2bf(float f) {            // RNE f32->bf16
  union { float f; u32 u; } v; v.f = f;
  u32 r = v.u + 0x7FFFu + ((v.u >> 16) & 1u);
  return (u16)(r >> 16);
}
__device__ __forceinline__ float bf2f(u16 s) {
  union { u32 u; float f; } v; v.u = ((u32)s) << 16; return v.f;
}
__device__ __forceinline__ float bflo(u32 u) {
  union { u32 u; float f; } v; v.u = u << 16; return v.f;
}
__device__ __forceinline__ float bfhi(u32 u) {
  union { u32 u; float f; } v; v.u = u & 0xFFFF0000u; return v.f;
}
__device__ __forceinline__ u32 pkbf(float a, float b) {
  return (u32)f2bf(a) | ((u32)f2bf(b) << 16);
}
// fp8 e4m3 (OCP) pack/unpack
__device__ __forceinline__ u32 pk4_fp8(float a, float b, float c, float d) {
#if __has_builtin(__builtin_amdgcn_cvt_pk_fp8_f32)
  u32 v = (u32)__builtin_amdgcn_cvt_pk_fp8_f32(a, b, 0, false);
  v = (u32)__builtin_amdgcn_cvt_pk_fp8_f32(c, d, (int)v, true);
  return v;
#else
  __hip_fp8_e4m3 x(a), y(b), z(c), w(d);
  return (u32)x.__x | ((u32)y.__x << 8) | ((u32)z.__x << 16) | ((u32)w.__x << 24);
#endif
}
template <int S>
__device__ __forceinline__ float fp8_f32(u32 v) {
#if __has_builtin(__builtin_amdgcn_cvt_f32_fp8)
  return __builtin_amdgcn_cvt_f32_fp8((int)v, S);
#else
  __hip_fp8_e4m3 x; x.__x = (unsigned char)(v >> (8 * S)); return (float)x;
#endif
}
// Pade(3/2) tanh for attention scores (error attenuated by Va-dot + /16 + softmax)
__device__ __forceinline__ float tanh_fast(float x) {
  float x2 = x * x;
  float r = x * (27.0f + x2) * __builtin_amdgcn_rcpf(27.0f + 9.0f * x2);
  return fminf(fmaxf(r, -1.0f), 1.0f);
}
__device__ __forceinline__ float sigmoid_acc(float x) {
  return __builtin_amdgcn_rcpf(1.0f + __builtin_exp2f(-1.4426950408889634f * x));
}
__device__ __forceinline__ float tanh_acc(float x) {
  return 1.0f - 2.0f * __builtin_amdgcn_rcpf(1.0f + __builtin_exp2f(2.8853900817779268f * x));
}

__global__ void cvt_bf16_kernel(const float* __restrict__ src, u16* __restrict__ dst, int n) {
  int i = blockIdx.x * blockDim.x + threadIdx.x;
  int stride = gridDim.x * blockDim.x;
  for (; i < n; i += stride) dst[i] = f2bf(src[i]);
}

// Persistent kernel: one WG = ONE batch element, all 24 steps. 512 WGs,
// 2 WGs/CU (100% occupancy): the two phase-desynchronized WGs fill each
// other's barrier/latency stalls. H in LDS as fp8 MFMA-A frags (64 KB).
template <int WBF>
__global__ __launch_bounds__(1024, 8) void lstm_attn_kernel(
    const float* __restrict__ H, const float* __restrict__ y0, const float* __restrict__ emb,
    const float* __restrict__ Wa, const float* __restrict__ UaF, const float* __restrict__ ba,
    const float* __restrict__ Va, const float* __restrict__ WF, const float* __restrict__ UF,
    const float* __restrict__ bias, const float* __restrict__ WyF, const float* __restrict__ fcw,
    const float* __restrict__ fcb, const u16* __restrict__ Ubf, const u16* __restrict__ Wbf,
    const u16* __restrict__ Wybf, const u16* __restrict__ Uabf, float* __restrict__ out) {
  const int bg = blockIdx.x;
  const int tid = threadIdx.x;
  const int lane = tid & 63;
  const int wv = tid >> 6;  // 0..15
  extern __shared__ char smem[];
  float* eL     = (float*)(smem + OFF_E);
  float* hL     = (float*)(smem + OFF_H);
  float* cL     = (float*)(smem + OFF_C);
  float* ctxL   = (float*)(smem + OFF_CTX);
  float* cuapL  = (float*)(smem + OFF_CUAP);
  float* ctxpL  = (float*)(smem + OFF_CUAP);   // union with cuap (disjoint phases)
  float* cuabaL = (float*)(smem + OFF_CUABA);
  float* vaL    = (float*)(smem + OFF_VA);
  float* redL   = (float*)(smem + OFF_RED);
  float* yL     = (float*)(smem + OFF_Y);
  float* invdL  = (float*)(smem + OFF_INVD);
  u32* gatepU   = (u32*)(smem + OFF_GATEP);

  // ---- one-time: stage H for this b into LDS as fp8 MFMA-A fragments ----
  // A-frag (16x16x32 family): m = lane&15, k = (lane>>4)*8 + j.
  // chunk (l, oct): 8 fp8 at ((mtile*4+kc)*64 + q*16 + lm)*8
  //   mtile=l>>4, lm=l&15, kc=oct>>2, q=oct&3.
#pragma unroll 2
  for (int it = 0; it < 8; ++it) {
    int ch = it * 1024 + tid;           // 0..8191
    int l = ch >> 4, oct = ch & 15;
    const float* src = H + (size_t)bg * (SEQL * IDIM) + l * IDIM + oct * 8;
    float4 a = *(const float4*)src;
    float4 c4 = *(const float4*)(src + 4);
    u32 lo = pk4_fp8(a.x, a.y, a.z, a.w);
    u32 hi = pk4_fp8(c4.x, c4.y, c4.z, c4.w);
    int mtile = l >> 4, lm2 = l & 15, kc = oct >> 2, q = oct & 3;
    *(uint2*)(smem + OFF_HFRAG +
              (size_t)(((mtile * 4 + kc) * 64 + q * 16 + lm2)) * 8) = make_uint2(lo, hi);
  }
  if (tid < 256) {  // carries
    hL[tid] = emb[(size_t)bg * 512 + tid];
    cL[tid] = emb[(size_t)bg * 512 + 256 + tid];
  }
  if (tid == 0) yL[0] = y0[bg];
  __syncthreads();

#pragma unroll 1
  for (int t = 0; t < TOUT; ++t) {
    // ===== P0: stage Wa_t fp8 B-frags (union w/ gatep) + c@Ua partials =====
    {  // B-frag: n = lane&15, k = (lane>>4)*8+j; frag (nt,kc) at ((nt*4+kc)*64+lane)*8
      int nt = tid >> 8, kc = (tid >> 6) & 3, l6 = tid & 63;
      int lm = l6 & 15, q = l6 >> 4;
      int n = nt * 16 + lm;
      float f[8];
#pragma unroll
      for (int j = 0; j < 8; ++j) {
        int k = kc * 32 + q * 8 + j;
        f[j] = Wa[((size_t)k * TOUT + t) * TMP + n];
      }
      *(uint2*)(smem + OFF_GATEP + (size_t)tid * 8) =
          make_uint2(pk4_fp8(f[0], f[1], f[2], f[3]), pk4_fp8(f[4], f[5], f[6], f[7]));
    }
    if (tid < 256) {  // cUa partials: j2 = j-pair, 8 d-parts of 32
      int j2 = tid & 31, part = tid >> 5;
      float s0 = 0.f, s1 = 0.f;
#pragma unroll 8
      for (int i = 0; i < 32; ++i) {
        int d = part * 32 + i;
        float u0, u1;
        if (WBF) {
          u32 uu = *(const u32*)(Uabf + ((size_t)d * TOUT + t) * TMP + j2 * 2);
          u0 = bflo(uu); u1 = bfhi(uu);
        } else {
          const float* up = UaF + ((size_t)d * TOUT + t) * TMP + j2 * 2;
          u0 = up[0]; u1 = up[1];
        }
        float c0 = cL[d];
        s0 += c0 * u0; s1 += c0 * u1;
      }
      cuapL[part * 64 + j2 * 2] = s0;
      cuapL[part * 64 + j2 * 2 + 1] = s1;
    }
    if (tid >= 960) vaL[tid - 960] = Va[(size_t)(tid - 960) * TOUT + t];
    __syncthreads();
    if (tid < 64) {
      float s = 0.f;
#pragma unroll
      for (int p = 0; p < 8; ++p) s += cuapL[p * 64 + tid];
      cuabaL[tid] = s + ba[t * TMP + tid];
    }
    __syncthreads();

    // ===== P1: e-pass  T = H_b @ Wa_t (fp8 MFMA), tanh, Va-dot =====
    {
      const int lm = lane & 15, q = lane >> 4;
      float cb[4], vv[4];
#pragma unroll
      for (int nt = 0; nt < 4; ++nt) {
        cb[nt] = cuabaL[nt * 16 + lm];
        vv[nt] = vaL[nt * 16 + lm];
      }
      long bfr[4][4];
#pragma unroll
      for (int nt = 0; nt < 4; ++nt)
#pragma unroll
        for (int kc = 0; kc < 4; ++kc)
          bfr[nt][kc] = *(const long*)(smem + OFF_GATEP + (size_t)(((nt * 4 + kc) * 64 + lane)) * 8);
#pragma unroll
      for (int mm = 0; mm < 2; ++mm) {
        int mtile = wv * 2 + mm;   // 16 waves x 2 = 32 mtiles
        f32x4 acc0 = 0, acc1 = 0, acc2 = 0, acc3 = 0;
#pragma unroll
        for (int kc = 0; kc < 4; ++kc) {
          long af = *(const long*)(smem + OFF_HFRAG +
                                   (size_t)(((mtile * 4 + kc) * 64 + lane)) * 8);
          acc0 = __builtin_amdgcn_mfma_f32_16x16x32_fp8_fp8(af, bfr[0][kc], acc0, 0, 0, 0);
          acc1 = __builtin_amdgcn_mfma_f32_16x16x32_fp8_fp8(af, bfr[1][kc], acc1, 0, 0, 0);
          acc2 = __builtin_amdgcn_mfma_f32_16x16x32_fp8_fp8(af, bfr[2][kc], acc2, 0, 0, 0);
          acc3 = __builtin_amdgcn_mfma_f32_16x16x32_fp8_fp8(af, bfr[3][kc], acc3, 0, 0, 0);
        }
        // C/D: col = nt*16 + (lane&15), row = mtile*16 + (lane>>4)*4 + r
#pragma unroll
        for (int r = 0; r < 4; ++r) {
          float v = tanh_fast(acc0[r] + cb[0]) * vv[0] + tanh_fast(acc1[r] + cb[1]) * vv[1] +
                    tanh_fast(acc2[r] + cb[2]) * vv[2] + tanh_fast(acc3[r] + cb[3]) * vv[3];
          v += __shfl_xor(v, 1);
          v += __shfl_xor(v, 2);
          v += __shfl_xor(v, 4);
          v += __shfl_xor(v, 8);
          if (lm == 0) eL[mtile * 16 + q * 4 + r] = v;
        }
      }
    }
    __syncthreads();

    // ===== P2: softmax over 512 (logits = e/16), 8 waves active =====
    {
      const bool act = tid < 512;
      const int w8 = tid >> 6;
      float v = act ? eL[tid] : 0.f;
      float m = v;
#pragma unroll
      for (int msk = 1; msk <= 32; msk <<= 1) m = fmaxf(m, __shfl_xor(m, msk));
      if (act && lane == 0) redL[w8] = m;
      __syncthreads();
      float pv = 0.f;
      if (act) {
        float M = redL[0];
#pragma unroll
        for (int p = 1; p < 8; ++p) M = fmaxf(M, redL[p]);
        pv = __builtin_exp2f((v - M) * 0.0901684400347379f);  // (1/16)*log2(e)
        eL[tid] = pv;
      }
      float s = pv;
#pragma unroll
      for (int msk = 1; msk <= 32; msk <<= 1) s += __shfl_xor(s, msk);
      if (act && lane == 0) redL[8 + w8] = s;
      __syncthreads();
      if (tid == 0) {
        float den = redL[8] + redL[9] + redL[10] + redL[11] +
                    redL[12] + redL[13] + redL[14] + redL[15];
        invdL[0] = __builtin_amdgcn_rcpf(den);
      }
    }

    // ===== P3: ctx_d = sum_l p_l H[l][d] (fp8 H from LDS), 4 quarters =====
    {
      int lsub = tid & 15, dch = (tid >> 4) & 15, qr = tid >> 8;  // qr 0..3
      int kc = dch >> 2, q2 = dch & 3;
      const char* hbase = smem + OFF_HFRAG;
      float a[8] = {0.f, 0.f, 0.f, 0.f, 0.f, 0.f, 0.f, 0.f};
#pragma unroll 4
      for (int i = 0; i < 8; ++i) {
        int mt = qr * 8 + i;
        uint2 hv = *(const uint2*)(hbase + (size_t)(((mt * 4 + kc) * 64 + q2 * 16 + lsub)) * 8);
        float p = eL[mt * 16 + lsub];
        a[0] += p * fp8_f32<0>(hv.x); a[1] += p * fp8_f32<1>(hv.x);
        a[2] += p * fp8_f32<2>(hv.x); a[3] += p * fp8_f32<3>(hv.x);
        a[4] += p * fp8_f32<0>(hv.y); a[5] += p * fp8_f32<1>(hv.y);
        a[6] += p * fp8_f32<2>(hv.y); a[7] += p * fp8_f32<3>(hv.y);
      }
#pragma unroll
      for (int msk = 1; msk <= 8; msk <<= 1)
#pragma unroll
        for (int j = 0; j < 8; ++j) a[j] += __shfl_xor(a[j], msk);
      if (lsub == 0) {
        float* dst = &ctxpL[qr * 128 + dch * 8];
#pragma unroll
        for (int j = 0; j < 8; ++j) dst[j] = a[j];
      }
    }
    __syncthreads();
    if (tid < 128) {
      ctxL[tid] = (ctxpL[tid] + ctxpL[128 + tid] + ctxpL[256 + tid] + ctxpL[384 + tid]) *
                  invdL[0];
    }
    __syncthreads();

    // ===== P4: gates partial GEMV (1 b) =====
    {
      int gc = tid & 255, dpart = tid >> 8;
      const int c0 = gc * 4;
      float g0[4] = {0.f, 0.f, 0.f, 0.f};
      // ctx @ W_t  (d = dpart*32 + 0..31)
      {
        const u16* wp = Wbf + ((size_t)(dpart * 32) * TOUT + t) * G4 + c0;
        const float* wpf = WF + ((size_t)(dpart * 32) * TOUT + t) * G4 + c0;
#pragma unroll 2
        for (int i4 = 0; i4 < 8; ++i4) {
          float4 cv0 = *(const float4*)&ctxL[dpart * 32 + i4 * 4];
#pragma unroll
          for (int j4 = 0; j4 < 4; ++j4) {
            float w0, w1, w2, w3;
            if (WBF) {
              uint2 w4 = *(const uint2*)wp;
              w0 = bflo(w4.x); w1 = bfhi(w4.x); w2 = bflo(w4.y); w3 = bfhi(w4.y);
              wp += (size_t)TOUT * G4;
            } else {
              float4 wf = *(const float4*)wpf;
              w0 = wf.x; w1 = wf.y; w2 = wf.z; w3 = wf.w;
              wpf += (size_t)TOUT * G4;
            }
            float cc0 = (j4 == 0) ? cv0.x : (j4 == 1) ? cv0.y : (j4 == 2) ? cv0.z : cv0.w;
            g0[0] += cc0 * w0; g0[1] += cc0 * w1; g0[2] += cc0 * w2; g0[3] += cc0 * w3;
          }
        }
      }
      // h @ U_t  (d = dpart*64 + 0..63)
      {
        const u16* up = Ubf + ((size_t)(dpart * 64) * TOUT + t) * G4 + c0;
        const float* upf = UF + ((size_t)(dpart * 64) * TOUT + t) * G4 + c0;
#pragma unroll 2
        for (int i4 = 0; i4 < 16; ++i4) {
          float4 hv0 = *(const float4*)&hL[dpart * 64 + i4 * 4];
#pragma unroll
          for (int j4 = 0; j4 < 4; ++j4) {
            float w0, w1, w2, w3;
            if (WBF) {
              uint2 w4 = *(const uint2*)up;
              w0 = bflo(w4.x); w1 = bfhi(w4.x); w2 = bflo(w4.y); w3 = bfhi(w4.y);
              up += (size_t)TOUT * G4;
            } else {
              float4 wf = *(const float4*)upf;
              w0 = wf.x; w1 = wf.y; w2 = wf.z; w3 = wf.w;
              upf += (size_t)TOUT * G4;
            }
            float hh0 = (j4 == 0) ? hv0.x : (j4 == 1) ? hv0.y : (j4 == 2) ? hv0.z : hv0.w;
            g0[0] += hh0 * w0; g0[1] += hh0 * w1; g0[2] += hh0 * w2; g0[3] += hh0 * w3;
          }
        }
      }
      // bf16-pack partials to LDS: gatepU[dpart][gc*2 .. +1]
      *(uint2*)&gatepU[dpart * 512 + gc * 2] =
          make_uint2(pkbf(g0[0], g0[1]), pkbf(g0[2], g0[3]));
    }
    __syncthreads();

    // ===== P5: gate reduce + LSTM cell + y =====
    float ypart = 0.f;
    if (tid < 256) {
      float yprev = yL[0];
      float gv[4];
#pragma unroll
      for (int gi = 0; gi < 4; ++gi) {
        int col = gi * 256 + tid;
        int ci = col >> 1, sel = col & 1;
        float s = 0.f;
#pragma unroll
        for (int p = 0; p < 4; ++p) {
          u32 u = gatepU[p * 512 + ci];
          s += sel ? bfhi(u) : bflo(u);
        }
        s += bias[(size_t)t * G4 + col];
        float wyv = WBF ? bf2f(Wybf[t * G4 + col]) : WyF[t * G4 + col];
        gv[gi] = s + yprev * wyv;
      }
      float ig = sigmoid_acc(gv[0]);
      float fg = sigmoid_acc(gv[1]);
      float gg = tanh_acc(gv[2]);
      float og = sigmoid_acc(gv[3]);
      float cn = fg * cL[tid] + ig * gg;
      float hn = og * tanh_acc(cn);
      cL[tid] = cn;
      hL[tid] = hn;
      out[12288 + ((size_t)bg * TOUT + t) * HS + tid] = hn;
      ypart = hn * fcw[t * HS + tid];
    }
#pragma unroll
    for (int msk = 1; msk <= 32; msk <<= 1) ypart += __shfl_xor(ypart, msk);
    if (tid < 256 && lane == 0) redL[16 + (tid >> 6)] = ypart;
    __syncthreads();
    if (tid == 0) {
      float y = redL[16] + redL[17] + redL[18] + redL[19] + fcb[t];
      yL[0] = y;
      out[(size_t)bg * TOUT + t] = y;
    }
    // no trailing barrier needed: next-step P0 writes (GATEP/cuap) are
    // ordered after this step's last reads by the barrier above; yL/redL
    // consumers are separated by >=2 barriers.
  }
}

extern "C" void kernel_launch(void* const* d_in, const int* in_sizes, int n_in, void* d_out,
                              int out_size, void* d_ws, size_t ws_size, hipStream_t stream) {
  const float* H    = (const float*)d_in[0];
  const float* y0   = (const float*)d_in[1];
  const float* emb  = (const float*)d_in[2];
  const float* Wa   = (const float*)d_in[3];
  const float* Ua   = (const float*)d_in[4];
  const float* ba   = (const float*)d_in[5];
  const float* Va   = (const float*)d_in[6];
  const float* W    = (const float*)d_in[7];
  const float* U    = (const float*)d_in[8];
  const float* bias = (const float*)d_in[9];
  const float* Wy   = (const float*)d_in[10];
  const float* fcw  = (const float*)d_in[11];
  const float* fcb  = (const float*)d_in[12];
  float* out = (float*)d_out;

  const size_t nU = (size_t)HS * TOUT * G4;    // 6291456
  const size_t nW = (size_t)IDIM * TOUT * G4;  // 3145728
  const size_t nWy = (size_t)TOUT * G4;        // 24576
  const size_t nUa = (size_t)HS * TOUT * TMP;  // 393216
  const size_t need = (nU + nW + nWy + nUa) * sizeof(u16);
  const bool usebf = (d_ws != nullptr) && (ws_size >= need);

  u16* Ubf = (u16*)d_ws;
  u16* Wbf = Ubf + nU;
  u16* Wybf = Wbf + nW;
  u16* Uabf = Wybf + nWy;

  if (usebf) {
    cvt_bf16_kernel<<<2048, 256, 0, stream>>>(U, Ubf, (int)nU);
    cvt_bf16_kernel<<<1024, 256, 0, stream>>>(W, Wbf, (int)nW);
    cvt_bf16_kernel<<<96, 256, 0, stream>>>(Wy, Wybf, (int)nWy);
    cvt_bf16_kernel<<<256, 256, 0, stream>>>(Ua, Uabf, (int)nUa);
  }

  hipFuncSetAttribute((const void*)lstm_attn_kernel<1>,
                      hipFuncAttributeMaxDynamicSharedMemorySize, SMEM_BYTES);
  hipFuncSetAttribute((const void*)lstm_attn_kernel<0>,
                      hipFuncAttributeMaxDynamicSharedMemorySize, SMEM_BYTES);

  if (usebf) {
    lstm_attn_kernel<1><<<NB, 1024, SMEM_BYTES, stream>>>(
        H, y0, emb, Wa, Ua, ba, Va, W, U, bias, Wy, fcw, fcb, Ubf, Wbf, Wybf, Uabf, out);
  } else {
    lstm_attn_kernel<0><<<NB, 1024, SMEM_BYTES, stream>>>(
        H, y0, emb, Wa, Ua, ba, Va, W, U, bias, Wy, fcw, fcb, Ubf, Wbf, Wybf, Uabf, out);
  }
}

// Round 4
// 1866.171 us; speedup vs baseline: 1.0341x; 1.0341x over previous
//
#include <hip/hip_runtime.h>
#include <hip/hip_fp8.h>
#include <cstdint>
#include <cstddef>

// Problem dims (TemporalLSTM_77455440216810)  [r3 resubmit of r2: infra failed
// twice on identical source; audit found no kernel-side fault mechanism]
#define IDIM 128   // INPUT_DIM
#define HS   256   // HIDDEN
#define SEQL 512   // SEQ
#define TOUT 24    // OUT (scan steps)
#define TMP  64    // TEMP
#define NB   512   // B
#define G4   1024  // 4*HS

typedef unsigned short u16;
typedef unsigned int   u32;
typedef __attribute__((ext_vector_type(4))) float f32x4;   // MFMA C/D frag

// ---- LDS layout (bytes). ONE batch element per WG. Total 81000;
// ---- 2 x 81000 = 162000 <= 163840 so TWO WGs (2048 thr) co-reside per CU.
#define OFF_HFRAG 0        // 65536: 512x128 fp8 MFMA-A frags
#define OFF_GATEP 65536    // 8192: gate partials u32[4][512] (bf16 pairs)
                           //       UNION Wa fp8 B-frags (8192) -- disjoint phases
#define OFF_E     73728    // 2048: e[512] f32
#define OFF_CUAP  75776    // 2048: cua partials [8][64] f32
                           //       UNION ctx partials [4][128] f32 -- disjoint
#define OFF_H     77824    // 1024: h[256] f32
#define OFF_C     78848    // 1024: c[256] f32
#define OFF_CTX   79872    // 512:  ctx[128] f32
#define OFF_CUABA 80384    // 256:  cua+ba [64] f32
#define OFF_VA    80640    // 256:  Va_t [64] f32
#define OFF_RED   80896    // 96:   reduction scratch [24] f32
#define OFF_Y     80992    // 4
#define OFF_INVD  80996    // 4
#define SMEM_BYTES 81000

__device__ __forceinline__ u16 f2bf(float f) {            // RNE f32->bf16
  union { float f; u32 u; } v; v.f = f;
  u32 r = v.u + 0x7FFFu + ((v.u >> 16) & 1u);
  return (u16)(r >> 16);
}
__device__ __forceinline__ float bf2f(u16 s) {
  union { u32 u; float f; } v; v.u = ((u32)s) << 16; return v.f;
}
__device__ __forceinline__ float bflo(u32 u) {
  union { u32 u; float f; } v; v.u = u << 16; return v.f;
}
__device__ __forceinline__ float bfhi(u32 u) {
  union { u32 u; float f; } v; v.u = u & 0xFFFF0000u; return v.f;
}
__device__ __forceinline__ u32 pkbf(float a, float b) {
  return (u32)f2bf(a) | ((u32)f2bf(b) << 16);
}
// fp8 e4m3 (OCP) pack/unpack
__device__ __forceinline__ u32 pk4_fp8(float a, float b, float c, float d) {
#if __has_builtin(__builtin_amdgcn_cvt_pk_fp8_f32)
  u32 v = (u32)__builtin_amdgcn_cvt_pk_fp8_f32(a, b, 0, false);
  v = (u32)__builtin_amdgcn_cvt_pk_fp8_f32(c, d, (int)v, true);
  return v;
#else
  __hip_fp8_e4m3 x(a), y(b), z(c), w(d);
  return (u32)x.__x | ((u32)y.__x << 8) | ((u32)z.__x << 16) | ((u32)w.__x << 24);
#endif
}
template <int S>
__device__ __forceinline__ float fp8_f32(u32 v) {
#if __has_builtin(__builtin_amdgcn_cvt_f32_fp8)
  return __builtin_amdgcn_cvt_f32_fp8((int)v, S);
#else
  __hip_fp8_e4m3 x; x.__x = (unsigned char)(v >> (8 * S)); return (float)x;
#endif
}
// Pade(3/2) tanh for attention scores (error attenuated by Va-dot + /16 + softmax)
__device__ __forceinline__ float tanh_fast(float x) {
  float x2 = x * x;
  float r = x * (27.0f + x2) * __builtin_amdgcn_rcpf(27.0f + 9.0f * x2);
  return fminf(fmaxf(r, -1.0f), 1.0f);
}
__device__ __forceinline__ float sigmoid_acc(float x) {
  return __builtin_amdgcn_rcpf(1.0f + __builtin_exp2f(-1.4426950408889634f * x));
}
__device__ __forceinline__ float tanh_acc(float x) {
  return 1.0f - 2.0f * __builtin_amdgcn_rcpf(1.0f + __builtin_exp2f(2.8853900817779268f * x));
}

__global__ void cvt_bf16_kernel(const float* __restrict__ src, u16* __restrict__ dst, int n) {
  int i = blockIdx.x * blockDim.x + threadIdx.x;
  int stride = gridDim.x * blockDim.x;
  for (; i < n; i += stride) dst[i] = f2bf(src[i]);
}

// Persistent kernel: one WG = ONE batch element, all 24 steps. 512 WGs,
// 2 WGs/CU. Register discipline: with __launch_bounds__(1024,8) the UNIFIED
// VGPR+AGPR budget is 64/wave. Round-1 lesson: hoisting 16 B-frags (32
// VGPR) in P1 overflowed -> scratch spill (WRITE_SIZE 297 MB). Fix: load
// the 4 per-kc B-frags inside the kc loop (peak live ~48 unified regs).
template <int WBF>
__global__ __launch_bounds__(1024, 8) void lstm_attn_kernel(
    const float* __restrict__ H, const float* __restrict__ y0, const float* __restrict__ emb,
    const float* __restrict__ Wa, const float* __restrict__ UaF, const float* __restrict__ ba,
    const float* __restrict__ Va, const float* __restrict__ WF, const float* __restrict__ UF,
    const float* __restrict__ bias, const float* __restrict__ WyF, const float* __restrict__ fcw,
    const float* __restrict__ fcb, const u16* __restrict__ Ubf, const u16* __restrict__ Wbf,
    const u16* __restrict__ Wybf, const u16* __restrict__ Uabf, float* __restrict__ out) {
  const int bg = blockIdx.x;
  const int tid = threadIdx.x;
  const int lane = tid & 63;
  const int wv = tid >> 6;  // 0..15
  extern __shared__ char smem[];
  float* eL     = (float*)(smem + OFF_E);
  float* hL     = (float*)(smem + OFF_H);
  float* cL     = (float*)(smem + OFF_C);
  float* ctxL   = (float*)(smem + OFF_CTX);
  float* cuapL  = (float*)(smem + OFF_CUAP);
  float* ctxpL  = (float*)(smem + OFF_CUAP);   // union with cuap (disjoint phases)
  float* cuabaL = (float*)(smem + OFF_CUABA);
  float* vaL    = (float*)(smem + OFF_VA);
  float* redL   = (float*)(smem + OFF_RED);
  float* yL     = (float*)(smem + OFF_Y);
  float* invdL  = (float*)(smem + OFF_INVD);
  u32* gatepU   = (u32*)(smem + OFF_GATEP);

  // ---- one-time: stage H for this b into LDS as fp8 MFMA-A fragments ----
  // A-frag (16x16x32 family): m = lane&15, k = (lane>>4)*8 + j.
  // chunk (l, oct): 8 fp8 at ((mtile*4+kc)*64 + q*16 + lm)*8
  //   with mtile=l>>4, lm=l&15, kc=oct>>2, q=oct&3.
#pragma unroll 2
  for (int it = 0; it < 8; ++it) {
    int ch = it * 1024 + tid;           // 0..8191
    int l = ch >> 4, oct = ch & 15;
    const float* src = H + (size_t)bg * (SEQL * IDIM) + l * IDIM + oct * 8;
    float4 a = *(const float4*)src;
    float4 c4 = *(const float4*)(src + 4);
    u32 lo = pk4_fp8(a.x, a.y, a.z, a.w);
    u32 hi = pk4_fp8(c4.x, c4.y, c4.z, c4.w);
    int mtile = l >> 4, lm2 = l & 15, kc = oct >> 2, q = oct & 3;
    *(uint2*)(smem + OFF_HFRAG +
              (size_t)(((mtile * 4 + kc) * 64 + q * 16 + lm2)) * 8) = make_uint2(lo, hi);
  }
  if (tid < 256) {  // carry init from embedding
    hL[tid] = emb[(size_t)bg * 512 + tid];
    cL[tid] = emb[(size_t)bg * 512 + 256 + tid];
  }
  if (tid == 0) yL[0] = y0[bg];
  __syncthreads();

#pragma unroll 1
  for (int t = 0; t < TOUT; ++t) {
    // ===== P0: stage Wa_t fp8 B-frags (union w/ gatep) + c@Ua partials =====
    {  // B-frag: n = lane&15, k = (lane>>4)*8+j; frag (nt,kc) at ((nt*4+kc)*64+lane)*8
      int nt = tid >> 8, kc = (tid >> 6) & 3, l6 = tid & 63;
      int lm = l6 & 15, q = l6 >> 4;
      int n = nt * 16 + lm;
      float f[8];
#pragma unroll
      for (int j = 0; j < 8; ++j) {
        int k = kc * 32 + q * 8 + j;
        f[j] = Wa[((size_t)k * TOUT + t) * TMP + n];
      }
      *(uint2*)(smem + OFF_GATEP + (size_t)tid * 8) =
          make_uint2(pk4_fp8(f[0], f[1], f[2], f[3]), pk4_fp8(f[4], f[5], f[6], f[7]));
    }
    if (tid < 256) {  // cUa partials: j2 = j-pair, 8 d-parts of 32
      int j2 = tid & 31, part = tid >> 5;
      float s0 = 0.f, s1 = 0.f;
#pragma unroll 8
      for (int i = 0; i < 32; ++i) {
        int d = part * 32 + i;
        float u0, u1;
        if (WBF) {
          u32 uu = *(const u32*)(Uabf + ((size_t)d * TOUT + t) * TMP + j2 * 2);
          u0 = bflo(uu); u1 = bfhi(uu);
        } else {
          const float* up = UaF + ((size_t)d * TOUT + t) * TMP + j2 * 2;
          u0 = up[0]; u1 = up[1];
        }
        float c0 = cL[d];
        s0 += c0 * u0; s1 += c0 * u1;
      }
      cuapL[part * 64 + j2 * 2] = s0;
      cuapL[part * 64 + j2 * 2 + 1] = s1;
    }
    if (tid >= 960) vaL[tid - 960] = Va[(size_t)(tid - 960) * TOUT + t];
    __syncthreads();
    if (tid < 64) {
      float s = 0.f;
#pragma unroll
      for (int p = 0; p < 8; ++p) s += cuapL[p * 64 + tid];
      cuabaL[tid] = s + ba[t * TMP + tid];
    }
    __syncthreads();

    // ===== P1: e-pass  T = H_b @ Wa_t (fp8 MFMA), tanh, Va-dot =====
    // Register-lean: B-frags loaded per-kc (4 live at a time), never 16.
    {
      const int lm = lane & 15, q = lane >> 4;
#pragma unroll
      for (int mm = 0; mm < 2; ++mm) {
        int mtile = wv * 2 + mm;   // 16 waves x 2 = 32 mtiles
        f32x4 acc0 = 0, acc1 = 0, acc2 = 0, acc3 = 0;
#pragma unroll
        for (int kc = 0; kc < 4; ++kc) {
          long af = *(const long*)(smem + OFF_HFRAG +
                                   (size_t)(((mtile * 4 + kc) * 64 + lane)) * 8);
          long b0 = *(const long*)(smem + OFF_GATEP + (size_t)(((0 * 4 + kc) * 64 + lane)) * 8);
          long b1 = *(const long*)(smem + OFF_GATEP + (size_t)(((1 * 4 + kc) * 64 + lane)) * 8);
          long b2 = *(const long*)(smem + OFF_GATEP + (size_t)(((2 * 4 + kc) * 64 + lane)) * 8);
          long b3 = *(const long*)(smem + OFF_GATEP + (size_t)(((3 * 4 + kc) * 64 + lane)) * 8);
          acc0 = __builtin_amdgcn_mfma_f32_16x16x32_fp8_fp8(af, b0, acc0, 0, 0, 0);
          acc1 = __builtin_amdgcn_mfma_f32_16x16x32_fp8_fp8(af, b1, acc1, 0, 0, 0);
          acc2 = __builtin_amdgcn_mfma_f32_16x16x32_fp8_fp8(af, b2, acc2, 0, 0, 0);
          acc3 = __builtin_amdgcn_mfma_f32_16x16x32_fp8_fp8(af, b3, acc3, 0, 0, 0);
        }
        // C/D: col = nt*16 + (lane&15), row = mtile*16 + (lane>>4)*4 + r
        float cb0 = cuabaL[0 * 16 + lm], cb1 = cuabaL[1 * 16 + lm];
        float cb2 = cuabaL[2 * 16 + lm], cb3 = cuabaL[3 * 16 + lm];
        float vv0 = vaL[0 * 16 + lm], vv1 = vaL[1 * 16 + lm];
        float vv2 = vaL[2 * 16 + lm], vv3 = vaL[3 * 16 + lm];
#pragma unroll
        for (int r = 0; r < 4; ++r) {
          float v = tanh_fast(acc0[r] + cb0) * vv0 + tanh_fast(acc1[r] + cb1) * vv1 +
                    tanh_fast(acc2[r] + cb2) * vv2 + tanh_fast(acc3[r] + cb3) * vv3;
          v += __shfl_xor(v, 1);
          v += __shfl_xor(v, 2);
          v += __shfl_xor(v, 4);
          v += __shfl_xor(v, 8);
          if (lm == 0) eL[mtile * 16 + q * 4 + r] = v;
        }
      }
    }
    __syncthreads();

    // ===== P2: softmax over 512 (logits = e/16), 8 waves active =====
    {
      const bool act = tid < 512;
      const int w8 = tid >> 6;
      float v = act ? eL[tid] : 0.f;
      float m = v;
#pragma unroll
      for (int msk = 1; msk <= 32; msk <<= 1) m = fmaxf(m, __shfl_xor(m, msk));
      if (act && lane == 0) redL[w8] = m;
      __syncthreads();
      float pv = 0.f;
      if (act) {
        float M = redL[0];
#pragma unroll
        for (int p = 1; p < 8; ++p) M = fmaxf(M, redL[p]);
        pv = __builtin_exp2f((v - M) * 0.0901684400347379f);  // (1/16)*log2(e)
        eL[tid] = pv;
      }
      float s = pv;
#pragma unroll
      for (int msk = 1; msk <= 32; msk <<= 1) s += __shfl_xor(s, msk);
      if (act && lane == 0) redL[8 + w8] = s;
      __syncthreads();
      if (tid == 0) {
        float den = redL[8] + redL[9] + redL[10] + redL[11] +
                    redL[12] + redL[13] + redL[14] + redL[15];
        invdL[0] = __builtin_amdgcn_rcpf(den);
      }
    }

    // ===== P3: ctx_d = sum_l p_l H[l][d] (fp8 H from LDS), 4 quarters =====
    {
      int lsub = tid & 15, dch = (tid >> 4) & 15, qr = tid >> 8;  // qr 0..3
      int kc = dch >> 2, q2 = dch & 3;
      const char* hbase = smem + OFF_HFRAG;
      float a[8] = {0.f, 0.f, 0.f, 0.f, 0.f, 0.f, 0.f, 0.f};
#pragma unroll 4
      for (int i = 0; i < 8; ++i) {
        int mt = qr * 8 + i;
        uint2 hv = *(const uint2*)(hbase + (size_t)(((mt * 4 + kc) * 64 + q2 * 16 + lsub)) * 8);
        float p = eL[mt * 16 + lsub];
        a[0] += p * fp8_f32<0>(hv.x); a[1] += p * fp8_f32<1>(hv.x);
        a[2] += p * fp8_f32<2>(hv.x); a[3] += p * fp8_f32<3>(hv.x);
        a[4] += p * fp8_f32<0>(hv.y); a[5] += p * fp8_f32<1>(hv.y);
        a[6] += p * fp8_f32<2>(hv.y); a[7] += p * fp8_f32<3>(hv.y);
      }
#pragma unroll
      for (int msk = 1; msk <= 8; msk <<= 1)
#pragma unroll
        for (int j = 0; j < 8; ++j) a[j] += __shfl_xor(a[j], msk);
      if (lsub == 0) {
        float* dst = &ctxpL[qr * 128 + dch * 8];
#pragma unroll
        for (int j = 0; j < 8; ++j) dst[j] = a[j];
      }
    }
    __syncthreads();
    if (tid < 128) {
      ctxL[tid] = (ctxpL[tid] + ctxpL[128 + tid] + ctxpL[256 + tid] + ctxpL[384 + tid]) *
                  invdL[0];
    }
    __syncthreads();

    // ===== P4: gates partial GEMV (1 b) =====
    {
      int gc = tid & 255, dpart = tid >> 8;
      const int c0 = gc * 4;
      float g0[4] = {0.f, 0.f, 0.f, 0.f};
      // ctx @ W_t  (d = dpart*32 + 0..31)
      {
        const u16* wp = Wbf + ((size_t)(dpart * 32) * TOUT + t) * G4 + c0;
        const float* wpf = WF + ((size_t)(dpart * 32) * TOUT + t) * G4 + c0;
#pragma unroll 2
        for (int i4 = 0; i4 < 8; ++i4) {
          float4 cv0 = *(const float4*)&ctxL[dpart * 32 + i4 * 4];
#pragma unroll
          for (int j4 = 0; j4 < 4; ++j4) {
            float w0, w1, w2, w3;
            if (WBF) {
              uint2 w4 = *(const uint2*)wp;
              w0 = bflo(w4.x); w1 = bfhi(w4.x); w2 = bflo(w4.y); w3 = bfhi(w4.y);
              wp += (size_t)TOUT * G4;
            } else {
              float4 wf = *(const float4*)wpf;
              w0 = wf.x; w1 = wf.y; w2 = wf.z; w3 = wf.w;
              wpf += (size_t)TOUT * G4;
            }
            float cc0 = (j4 == 0) ? cv0.x : (j4 == 1) ? cv0.y : (j4 == 2) ? cv0.z : cv0.w;
            g0[0] += cc0 * w0; g0[1] += cc0 * w1; g0[2] += cc0 * w2; g0[3] += cc0 * w3;
          }
        }
      }
      // h @ U_t  (d = dpart*64 + 0..63)
      {
        const u16* up = Ubf + ((size_t)(dpart * 64) * TOUT + t) * G4 + c0;
        const float* upf = UF + ((size_t)(dpart * 64) * TOUT + t) * G4 + c0;
#pragma unroll 2
        for (int i4 = 0; i4 < 16; ++i4) {
          float4 hv0 = *(const float4*)&hL[dpart * 64 + i4 * 4];
#pragma unroll
          for (int j4 = 0; j4 < 4; ++j4) {
            float w0, w1, w2, w3;
            if (WBF) {
              uint2 w4 = *(const uint2*)up;
              w0 = bflo(w4.x); w1 = bfhi(w4.x); w2 = bflo(w4.y); w3 = bfhi(w4.y);
              up += (size_t)TOUT * G4;
            } else {
              float4 wf = *(const float4*)upf;
              w0 = wf.x; w1 = wf.y; w2 = wf.z; w3 = wf.w;
              upf += (size_t)TOUT * G4;
            }
            float hh0 = (j4 == 0) ? hv0.x : (j4 == 1) ? hv0.y : (j4 == 2) ? hv0.z : hv0.w;
            g0[0] += hh0 * w0; g0[1] += hh0 * w1; g0[2] += hh0 * w2; g0[3] += hh0 * w3;
          }
        }
      }
      // bf16-pack partials to LDS: gatepU[dpart][gc*2 .. +1]
      *(uint2*)&gatepU[dpart * 512 + gc * 2] =
          make_uint2(pkbf(g0[0], g0[1]), pkbf(g0[2], g0[3]));
    }
    __syncthreads();

    // ===== P5: gate reduce + LSTM cell + y =====
    float ypart = 0.f;
    if (tid < 256) {
      float yprev = yL[0];
      float gv[4];
#pragma unroll
      for (int gi = 0; gi < 4; ++gi) {
        int col = gi * 256 + tid;
        int ci = col >> 1, sel = col & 1;
        float s = 0.f;
#pragma unroll
        for (int p = 0; p < 4; ++p) {
          u32 u = gatepU[p * 512 + ci];
          s += sel ? bfhi(u) : bflo(u);
        }
        s += bias[(size_t)t * G4 + col];
        float wyv = WBF ? bf2f(Wybf[t * G4 + col]) : WyF[t * G4 + col];
        gv[gi] = s + yprev * wyv;
      }
      float ig = sigmoid_acc(gv[0]);
      float fg = sigmoid_acc(gv[1]);
      float gg = tanh_acc(gv[2]);
      float og = sigmoid_acc(gv[3]);
      float cn = fg * cL[tid] + ig * gg;
      float hn = og * tanh_acc(cn);
      cL[tid] = cn;
      hL[tid] = hn;
      out[12288 + ((size_t)bg * TOUT + t) * HS + tid] = hn;
      ypart = hn * fcw[t * HS + tid];
    }
#pragma unroll
    for (int msk = 1; msk <= 32; msk <<= 1) ypart += __shfl_xor(ypart, msk);
    if (tid < 256 && lane == 0) redL[16 + (tid >> 6)] = ypart;
    __syncthreads();
    if (tid == 0) {
      float y = redL[16] + redL[17] + redL[18] + redL[19] + fcb[t];
      yL[0] = y;
      out[(size_t)bg * TOUT + t] = y;
    }
    // no trailing barrier needed: next-step P0 writes (GATEP/cuap) and cL
    // reads are ordered by the barrier above; yL/redL consumers are
    // separated by >=2 barriers.
  }
}

extern "C" void kernel_launch(void* const* d_in, const int* in_sizes, int n_in, void* d_out,
                              int out_size, void* d_ws, size_t ws_size, hipStream_t stream) {
  const float* H    = (const float*)d_in[0];
  const float* y0   = (const float*)d_in[1];
  const float* emb  = (const float*)d_in[2];
  const float* Wa   = (const float*)d_in[3];
  const float* Ua   = (const float*)d_in[4];
  const float* ba   = (const float*)d_in[5];
  const float* Va   = (const float*)d_in[6];
  const float* W    = (const float*)d_in[7];
  const float* U    = (const float*)d_in[8];
  const float* bias = (const float*)d_in[9];
  const float* Wy   = (const float*)d_in[10];
  const float* fcw  = (const float*)d_in[11];
  const float* fcb  = (const float*)d_in[12];
  float* out = (float*)d_out;

  const size_t nU = (size_t)HS * TOUT * G4;    // 6291456
  const size_t nW = (size_t)IDIM * TOUT * G4;  // 3145728
  const size_t nWy = (size_t)TOUT * G4;        // 24576
  const size_t nUa = (size_t)HS * TOUT * TMP;  // 393216
  const size_t need = (nU + nW + nWy + nUa) * sizeof(u16);
  const bool usebf = (d_ws != nullptr) && (ws_size >= need);

  u16* Ubf = (u16*)d_ws;
  u16* Wbf = Ubf + nU;
  u16* Wybf = Wbf + nW;
  u16* Uabf = Wybf + nWy;

  if (usebf) {
    cvt_bf16_kernel<<<2048, 256, 0, stream>>>(U, Ubf, (int)nU);
    cvt_bf16_kernel<<<1024, 256, 0, stream>>>(W, Wbf, (int)nW);
    cvt_bf16_kernel<<<96, 256, 0, stream>>>(Wy, Wybf, (int)nWy);
    cvt_bf16_kernel<<<256, 256, 0, stream>>>(Ua, Uabf, (int)nUa);
  }

  hipFuncSetAttribute((const void*)lstm_attn_kernel<1>,
                      hipFuncAttributeMaxDynamicSharedMemorySize, SMEM_BYTES);
  hipFuncSetAttribute((const void*)lstm_attn_kernel<0>,
                      hipFuncAttributeMaxDynamicSharedMemorySize, SMEM_BYTES);

  if (usebf) {
    lstm_attn_kernel<1><<<NB, 1024, SMEM_BYTES, stream>>>(
        H, y0, emb, Wa, Ua, ba, Va, W, U, bias, Wy, fcw, fcb, Ubf, Wbf, Wybf, Uabf, out);
  } else {
    lstm_attn_kernel<0><<<NB, 1024, SMEM_BYTES, stream>>>(
        H, y0, emb, Wa, Ua, ba, Va, W, U, bias, Wy, fcw, fcb, Ubf, Wbf, Wybf, Uabf, out);
  }
}

// Round 5
// 1041.395 us; speedup vs baseline: 1.8532x; 1.7920x over previous
//
#include <hip/hip_runtime.h>
#include <hip/hip_fp8.h>
#include <cstdint>
#include <cstddef>

// Problem dims (TemporalLSTM_77455440216810)
// r5: 512-thr WG, 1 b/WG, launch_bounds(512,4) -> 128 regs/wave (NO spill),
// 2 WGs/CU via LDS (2x81000 <= 163840). Tests the barrier-desync thesis
// without the 64-reg spilling that killed r1/r4 (VGPR=32, WRITE 283-297 MB).
#define IDIM 128   // INPUT_DIM
#define HS   256   // HIDDEN
#define SEQL 512   // SEQ
#define TOUT 24    // OUT (scan steps)
#define TMP  64    // TEMP
#define NB   512   // B
#define G4   1024  // 4*HS

typedef unsigned short u16;
typedef unsigned int   u32;
typedef __attribute__((ext_vector_type(4))) float f32x4;   // MFMA C/D frag

// ---- LDS layout (bytes). ONE batch element per WG of 512 threads. ----
#define OFF_HFRAG 0        // 65536: 512x128 fp8 MFMA-A frags
#define OFF_GATEP 65536    // 8192: gate partials u32[2][512] (bf16 pairs; 4KB used)
                           //       UNION Wa fp8 B-frags (8192) -- disjoint phases
#define OFF_E     73728    // 2048: e[512] f32
#define OFF_CUAP  75776    // 2048: cua partials [8][64] f32
                           //       UNION ctx partials [2][128] f32 -- disjoint
#define OFF_H     77824    // 1024: h[256] f32
#define OFF_C     78848    // 1024: c[256] f32
#define OFF_CTX   79872    // 512:  ctx[128] f32
#define OFF_CUABA 80384    // 256:  cua+ba [64] f32
#define OFF_VA    80640    // 256:  Va_t [64] f32
#define OFF_RED   80896    // 96:   reduction scratch [24] f32
#define OFF_Y     80992    // 4
#define OFF_INVD  80996    // 4
#define SMEM_BYTES 81000

__device__ __forceinline__ u16 f2bf(float f) {            // RNE f32->bf16
  union { float f; u32 u; } v; v.f = f;
  u32 r = v.u + 0x7FFFu + ((v.u >> 16) & 1u);
  return (u16)(r >> 16);
}
__device__ __forceinline__ float bf2f(u16 s) {
  union { u32 u; float f; } v; v.u = ((u32)s) << 16; return v.f;
}
__device__ __forceinline__ float bflo(u32 u) {
  union { u32 u; float f; } v; v.u = u << 16; return v.f;
}
__device__ __forceinline__ float bfhi(u32 u) {
  union { u32 u; float f; } v; v.u = u & 0xFFFF0000u; return v.f;
}
__device__ __forceinline__ u32 pkbf(float a, float b) {
  return (u32)f2bf(a) | ((u32)f2bf(b) << 16);
}
// fp8 e4m3 (OCP) pack/unpack
__device__ __forceinline__ u32 pk4_fp8(float a, float b, float c, float d) {
#if __has_builtin(__builtin_amdgcn_cvt_pk_fp8_f32)
  u32 v = (u32)__builtin_amdgcn_cvt_pk_fp8_f32(a, b, 0, false);
  v = (u32)__builtin_amdgcn_cvt_pk_fp8_f32(c, d, (int)v, true);
  return v;
#else
  __hip_fp8_e4m3 x(a), y(b), z(c), w(d);
  return (u32)x.__x | ((u32)y.__x << 8) | ((u32)z.__x << 16) | ((u32)w.__x << 24);
#endif
}
template <int S>
__device__ __forceinline__ float fp8_f32(u32 v) {
#if __has_builtin(__builtin_amdgcn_cvt_f32_fp8)
  return __builtin_amdgcn_cvt_f32_fp8((int)v, S);
#else
  __hip_fp8_e4m3 x; x.__x = (unsigned char)(v >> (8 * S)); return (float)x;
#endif
}
// Pade(3/2) tanh for attention scores (error attenuated by Va-dot + /16 + softmax)
__device__ __forceinline__ float tanh_fast(float x) {
  float x2 = x * x;
  float r = x * (27.0f + x2) * __builtin_amdgcn_rcpf(27.0f + 9.0f * x2);
  return fminf(fmaxf(r, -1.0f), 1.0f);
}
__device__ __forceinline__ float sigmoid_acc(float x) {
  return __builtin_amdgcn_rcpf(1.0f + __builtin_exp2f(-1.4426950408889634f * x));
}
__device__ __forceinline__ float tanh_acc(float x) {
  return 1.0f - 2.0f * __builtin_amdgcn_rcpf(1.0f + __builtin_exp2f(2.8853900817779268f * x));
}

__global__ void cvt_bf16_kernel(const float* __restrict__ src, u16* __restrict__ dst, int n) {
  int i = blockIdx.x * blockDim.x + threadIdx.x;
  int stride = gridDim.x * blockDim.x;
  for (; i < n; i += stride) dst[i] = f2bf(src[i]);
}

// Persistent kernel: one WG (512 thr) = ONE batch element, all 24 steps.
// 512 WGs -> 2 WGs/CU, two INDEPENDENT barrier domains per CU whose stalls
// overlap. 128 regs/wave (launch_bounds(512,4)) -> no scratch spill.
template <int WBF>
__global__ __launch_bounds__(512, 4) void lstm_attn_kernel(
    const float* __restrict__ H, const float* __restrict__ y0, const float* __restrict__ emb,
    const float* __restrict__ Wa, const float* __restrict__ UaF, const float* __restrict__ ba,
    const float* __restrict__ Va, const float* __restrict__ WF, const float* __restrict__ UF,
    const float* __restrict__ bias, const float* __restrict__ WyF, const float* __restrict__ fcw,
    const float* __restrict__ fcb, const u16* __restrict__ Ubf, const u16* __restrict__ Wbf,
    const u16* __restrict__ Wybf, const u16* __restrict__ Uabf, float* __restrict__ out) {
  const int bg = blockIdx.x;
  const int tid = threadIdx.x;        // 0..511
  const int lane = tid & 63;
  const int wv = tid >> 6;            // 0..7
  extern __shared__ char smem[];
  float* eL     = (float*)(smem + OFF_E);
  float* hL     = (float*)(smem + OFF_H);
  float* cL     = (float*)(smem + OFF_C);
  float* ctxL   = (float*)(smem + OFF_CTX);
  float* cuapL  = (float*)(smem + OFF_CUAP);
  float* ctxpL  = (float*)(smem + OFF_CUAP);   // union with cuap (disjoint phases)
  float* cuabaL = (float*)(smem + OFF_CUABA);
  float* vaL    = (float*)(smem + OFF_VA);
  float* redL   = (float*)(smem + OFF_RED);
  float* yL     = (float*)(smem + OFF_Y);
  float* invdL  = (float*)(smem + OFF_INVD);
  u32* gatepU   = (u32*)(smem + OFF_GATEP);

  // ---- one-time: stage H for this b into LDS as fp8 MFMA-A fragments ----
  // A-frag (16x16x32 family): m = lane&15, k = (lane>>4)*8 + j.
  // chunk (l, oct): 8 fp8 at ((mtile*4+kc)*64 + q*16 + lm)*8
  //   with mtile=l>>4, lm=l&15, kc=oct>>2, q=oct&3.
#pragma unroll 2
  for (int it = 0; it < 16; ++it) {
    int ch = it * 512 + tid;            // 0..8191
    int l = ch >> 4, oct = ch & 15;
    const float* src = H + (size_t)bg * (SEQL * IDIM) + l * IDIM + oct * 8;
    float4 a = *(const float4*)src;
    float4 c4 = *(const float4*)(src + 4);
    u32 lo = pk4_fp8(a.x, a.y, a.z, a.w);
    u32 hi = pk4_fp8(c4.x, c4.y, c4.z, c4.w);
    int mtile = l >> 4, lm2 = l & 15, kc = oct >> 2, q = oct & 3;
    *(uint2*)(smem + OFF_HFRAG +
              (size_t)(((mtile * 4 + kc) * 64 + q * 16 + lm2)) * 8) = make_uint2(lo, hi);
  }
  if (tid < 256) {  // carry init from embedding
    hL[tid] = emb[(size_t)bg * 512 + tid];
    cL[tid] = emb[(size_t)bg * 512 + 256 + tid];
  }
  if (tid == 0) yL[0] = y0[bg];
  __syncthreads();

#pragma unroll 1
  for (int t = 0; t < TOUT; ++t) {
    // ===== P0: stage Wa_t fp8 B-frags (union w/ gatep) + c@Ua partials =====
    // B-frag: n = lane&15, k = (lane>>4)*8+j; frag (nt,kc) at ((nt*4+kc)*64+lane)*8
    // 1024 frag-dwords over 512 threads: 2 per thread.
#pragma unroll
    for (int half = 0; half < 2; ++half) {
      int id = half * 512 + tid;        // 0..1023
      int nt = id >> 8, kc = (id >> 6) & 3, l6 = id & 63;
      int lm = l6 & 15, q = l6 >> 4;
      int n = nt * 16 + lm;
      float f[8];
#pragma unroll
      for (int j = 0; j < 8; ++j) {
        int k = kc * 32 + q * 8 + j;
        f[j] = Wa[((size_t)k * TOUT + t) * TMP + n];
      }
      *(uint2*)(smem + OFF_GATEP + (size_t)id * 8) =
          make_uint2(pk4_fp8(f[0], f[1], f[2], f[3]), pk4_fp8(f[4], f[5], f[6], f[7]));
    }
    if (tid < 256) {  // cUa partials: j2 = j-pair, 8 d-parts of 32
      int j2 = tid & 31, part = tid >> 5;
      float s0 = 0.f, s1 = 0.f;
#pragma unroll 8
      for (int i = 0; i < 32; ++i) {
        int d = part * 32 + i;
        float u0, u1;
        if (WBF) {
          u32 uu = *(const u32*)(Uabf + ((size_t)d * TOUT + t) * TMP + j2 * 2);
          u0 = bflo(uu); u1 = bfhi(uu);
        } else {
          const float* up = UaF + ((size_t)d * TOUT + t) * TMP + j2 * 2;
          u0 = up[0]; u1 = up[1];
        }
        float c0 = cL[d];
        s0 += c0 * u0; s1 += c0 * u1;
      }
      cuapL[part * 64 + j2 * 2] = s0;
      cuapL[part * 64 + j2 * 2 + 1] = s1;
    }
    if (tid >= 448) vaL[tid - 448] = Va[(size_t)(tid - 448) * TOUT + t];
    __syncthreads();
    if (tid < 64) {
      float s = 0.f;
#pragma unroll
      for (int p = 0; p < 8; ++p) s += cuapL[p * 64 + tid];
      cuabaL[tid] = s + ba[t * TMP + tid];
    }
    __syncthreads();

    // ===== P1: e-pass  T = H_b @ Wa_t (fp8 MFMA), tanh, Va-dot =====
    // 128-reg budget: hoist all 16 B-frags (32 VGPR) once per step.
    {
      const int lm = lane & 15, q = lane >> 4;
      long bfr[4][4];
#pragma unroll
      for (int nt = 0; nt < 4; ++nt)
#pragma unroll
        for (int kc = 0; kc < 4; ++kc)
          bfr[nt][kc] = *(const long*)(smem + OFF_GATEP + (size_t)(((nt * 4 + kc) * 64 + lane)) * 8);
      float cb0 = cuabaL[0 * 16 + lm], cb1 = cuabaL[1 * 16 + lm];
      float cb2 = cuabaL[2 * 16 + lm], cb3 = cuabaL[3 * 16 + lm];
      float vv0 = vaL[0 * 16 + lm], vv1 = vaL[1 * 16 + lm];
      float vv2 = vaL[2 * 16 + lm], vv3 = vaL[3 * 16 + lm];
#pragma unroll
      for (int mm = 0; mm < 4; ++mm) {
        int mtile = wv * 4 + mm;        // 8 waves x 4 = 32 mtiles
        f32x4 acc0 = 0, acc1 = 0, acc2 = 0, acc3 = 0;
#pragma unroll
        for (int kc = 0; kc < 4; ++kc) {
          long af = *(const long*)(smem + OFF_HFRAG +
                                   (size_t)(((mtile * 4 + kc) * 64 + lane)) * 8);
          acc0 = __builtin_amdgcn_mfma_f32_16x16x32_fp8_fp8(af, bfr[0][kc], acc0, 0, 0, 0);
          acc1 = __builtin_amdgcn_mfma_f32_16x16x32_fp8_fp8(af, bfr[1][kc], acc1, 0, 0, 0);
          acc2 = __builtin_amdgcn_mfma_f32_16x16x32_fp8_fp8(af, bfr[2][kc], acc2, 0, 0, 0);
          acc3 = __builtin_amdgcn_mfma_f32_16x16x32_fp8_fp8(af, bfr[3][kc], acc3, 0, 0, 0);
        }
        // C/D: col = nt*16 + (lane&15), row = mtile*16 + (lane>>4)*4 + r
#pragma unroll
        for (int r = 0; r < 4; ++r) {
          float v = tanh_fast(acc0[r] + cb0) * vv0 + tanh_fast(acc1[r] + cb1) * vv1 +
                    tanh_fast(acc2[r] + cb2) * vv2 + tanh_fast(acc3[r] + cb3) * vv3;
          v += __shfl_xor(v, 1);
          v += __shfl_xor(v, 2);
          v += __shfl_xor(v, 4);
          v += __shfl_xor(v, 8);
          if (lm == 0) eL[mtile * 16 + q * 4 + r] = v;
        }
      }
    }
    __syncthreads();

    // ===== P2: softmax over 512 (logits = e/16), all 8 waves =====
    {
      const int w8 = wv;
      float v = eL[tid];
      float m = v;
#pragma unroll
      for (int msk = 1; msk <= 32; msk <<= 1) m = fmaxf(m, __shfl_xor(m, msk));
      if (lane == 0) redL[w8] = m;
      __syncthreads();
      float M = redL[0];
#pragma unroll
      for (int p = 1; p < 8; ++p) M = fmaxf(M, redL[p]);
      float pv = __builtin_exp2f((v - M) * 0.0901684400347379f);  // (1/16)*log2(e)
      eL[tid] = pv;
      float s = pv;
#pragma unroll
      for (int msk = 1; msk <= 32; msk <<= 1) s += __shfl_xor(s, msk);
      if (lane == 0) redL[8 + w8] = s;
      __syncthreads();
      if (tid == 0) {
        float den = redL[8] + redL[9] + redL[10] + redL[11] +
                    redL[12] + redL[13] + redL[14] + redL[15];
        invdL[0] = __builtin_amdgcn_rcpf(den);
      }
    }

    // ===== P3: ctx_d = sum_l p_l H[l][d] (fp8 H from LDS), 2 halves =====
    {
      int lsub = tid & 15, dch = (tid >> 4) & 15, half = tid >> 8;  // half 0..1
      int kc = dch >> 2, q2 = dch & 3;
      const char* hbase = smem + OFF_HFRAG;
      float a[8] = {0.f, 0.f, 0.f, 0.f, 0.f, 0.f, 0.f, 0.f};
#pragma unroll 4
      for (int i = 0; i < 16; ++i) {
        int mt = half * 16 + i;
        uint2 hv = *(const uint2*)(hbase + (size_t)(((mt * 4 + kc) * 64 + q2 * 16 + lsub)) * 8);
        float p = eL[mt * 16 + lsub];
        a[0] += p * fp8_f32<0>(hv.x); a[1] += p * fp8_f32<1>(hv.x);
        a[2] += p * fp8_f32<2>(hv.x); a[3] += p * fp8_f32<3>(hv.x);
        a[4] += p * fp8_f32<0>(hv.y); a[5] += p * fp8_f32<1>(hv.y);
        a[6] += p * fp8_f32<2>(hv.y); a[7] += p * fp8_f32<3>(hv.y);
      }
#pragma unroll
      for (int msk = 1; msk <= 8; msk <<= 1)
#pragma unroll
        for (int j = 0; j < 8; ++j) a[j] += __shfl_xor(a[j], msk);
      if (lsub == 0) {
        float* dst = &ctxpL[half * 128 + dch * 8];
#pragma unroll
        for (int j = 0; j < 8; ++j) dst[j] = a[j];
      }
    }
    __syncthreads();
    if (tid < 128) {
      ctxL[tid] = (ctxpL[tid] + ctxpL[128 + tid]) * invdL[0];
    }
    __syncthreads();

    // ===== P4: gates partial GEMV (1 b, 2 d-parts) =====
    {
      int gc = tid & 255, dpart = tid >> 8;      // dpart 0..1
      const int c0 = gc * 4;
      float g0[4] = {0.f, 0.f, 0.f, 0.f};
      // ctx @ W_t  (d = dpart*64 + 0..63)
      {
        const u16* wp = Wbf + ((size_t)(dpart * 64) * TOUT + t) * G4 + c0;
        const float* wpf = WF + ((size_t)(dpart * 64) * TOUT + t) * G4 + c0;
#pragma unroll 2
        for (int i4 = 0; i4 < 16; ++i4) {
          float4 cv0 = *(const float4*)&ctxL[dpart * 64 + i4 * 4];
#pragma unroll
          for (int j4 = 0; j4 < 4; ++j4) {
            float w0, w1, w2, w3;
            if (WBF) {
              uint2 w4 = *(const uint2*)wp;
              w0 = bflo(w4.x); w1 = bfhi(w4.x); w2 = bflo(w4.y); w3 = bfhi(w4.y);
              wp += (size_t)TOUT * G4;
            } else {
              float4 wf = *(const float4*)wpf;
              w0 = wf.x; w1 = wf.y; w2 = wf.z; w3 = wf.w;
              wpf += (size_t)TOUT * G4;
            }
            float cc0 = (j4 == 0) ? cv0.x : (j4 == 1) ? cv0.y : (j4 == 2) ? cv0.z : cv0.w;
            g0[0] += cc0 * w0; g0[1] += cc0 * w1; g0[2] += cc0 * w2; g0[3] += cc0 * w3;
          }
        }
      }
      // h @ U_t  (d = dpart*128 + 0..127)
      {
        const u16* up = Ubf + ((size_t)(dpart * 128) * TOUT + t) * G4 + c0;
        const float* upf = UF + ((size_t)(dpart * 128) * TOUT + t) * G4 + c0;
#pragma unroll 2
        for (int i4 = 0; i4 < 32; ++i4) {
          float4 hv0 = *(const float4*)&hL[dpart * 128 + i4 * 4];
#pragma unroll
          for (int j4 = 0; j4 < 4; ++j4) {
            float w0, w1, w2, w3;
            if (WBF) {
              uint2 w4 = *(const uint2*)up;
              w0 = bflo(w4.x); w1 = bfhi(w4.x); w2 = bflo(w4.y); w3 = bfhi(w4.y);
              up += (size_t)TOUT * G4;
            } else {
              float4 wf = *(const float4*)upf;
              w0 = wf.x; w1 = wf.y; w2 = wf.z; w3 = wf.w;
              upf += (size_t)TOUT * G4;
            }
            float hh0 = (j4 == 0) ? hv0.x : (j4 == 1) ? hv0.y : (j4 == 2) ? hv0.z : hv0.w;
            g0[0] += hh0 * w0; g0[1] += hh0 * w1; g0[2] += hh0 * w2; g0[3] += hh0 * w3;
          }
        }
      }
      // bf16-pack partials to LDS: gatepU[dpart][gc*2 .. +1]
      *(uint2*)&gatepU[dpart * 512 + gc * 2] =
          make_uint2(pkbf(g0[0], g0[1]), pkbf(g0[2], g0[3]));
    }
    __syncthreads();

    // ===== P5: gate reduce + LSTM cell + y =====
    float ypart = 0.f;
    if (tid < 256) {
      float yprev = yL[0];
      float gv[4];
#pragma unroll
      for (int gi = 0; gi < 4; ++gi) {
        int col = gi * 256 + tid;
        int ci = col >> 1, sel = col & 1;
        float s = 0.f;
#pragma unroll
        for (int p = 0; p < 2; ++p) {
          u32 u = gatepU[p * 512 + ci];
          s += sel ? bfhi(u) : bflo(u);
        }
        s += bias[(size_t)t * G4 + col];
        float wyv = WBF ? bf2f(Wybf[t * G4 + col]) : WyF[t * G4 + col];
        gv[gi] = s + yprev * wyv;
      }
      float ig = sigmoid_acc(gv[0]);
      float fg = sigmoid_acc(gv[1]);
      float gg = tanh_acc(gv[2]);
      float og = sigmoid_acc(gv[3]);
      float cn = fg * cL[tid] + ig * gg;
      float hn = og * tanh_acc(cn);
      cL[tid] = cn;
      hL[tid] = hn;
      out[12288 + ((size_t)bg * TOUT + t) * HS + tid] = hn;
      ypart = hn * fcw[t * HS + tid];
    }
#pragma unroll
    for (int msk = 1; msk <= 32; msk <<= 1) ypart += __shfl_xor(ypart, msk);
    if (tid < 256 && lane == 0) redL[16 + wv] = ypart;   // wv 0..3 here
    __syncthreads();
    if (tid == 0) {
      float y = redL[16] + redL[17] + redL[18] + redL[19] + fcb[t];
      yL[0] = y;
      out[(size_t)bg * TOUT + t] = y;
    }
    // next-step P0 writes (GATEP/cuap) and cL/hL reads are ordered by the
    // barrier above; yL/redL consumers are separated by >=2 barriers.
  }
}

extern "C" void kernel_launch(void* const* d_in, const int* in_sizes, int n_in, void* d_out,
                              int out_size, void* d_ws, size_t ws_size, hipStream_t stream) {
  const float* H    = (const float*)d_in[0];
  const float* y0   = (const float*)d_in[1];
  const float* emb  = (const float*)d_in[2];
  const float* Wa   = (const float*)d_in[3];
  const float* Ua   = (const float*)d_in[4];
  const float* ba   = (const float*)d_in[5];
  const float* Va   = (const float*)d_in[6];
  const float* W    = (const float*)d_in[7];
  const float* U    = (const float*)d_in[8];
  const float* bias = (const float*)d_in[9];
  const float* Wy   = (const float*)d_in[10];
  const float* fcw  = (const float*)d_in[11];
  const float* fcb  = (const float*)d_in[12];
  float* out = (float*)d_out;

  const size_t nU = (size_t)HS * TOUT * G4;    // 6291456
  const size_t nW = (size_t)IDIM * TOUT * G4;  // 3145728
  const size_t nWy = (size_t)TOUT * G4;        // 24576
  const size_t nUa = (size_t)HS * TOUT * TMP;  // 393216
  const size_t need = (nU + nW + nWy + nUa) * sizeof(u16);
  const bool usebf = (d_ws != nullptr) && (ws_size >= need);

  u16* Ubf = (u16*)d_ws;
  u16* Wbf = Ubf + nU;
  u16* Wybf = Wbf + nW;
  u16* Uabf = Wybf + nWy;

  if (usebf) {
    cvt_bf16_kernel<<<2048, 256, 0, stream>>>(U, Ubf, (int)nU);
    cvt_bf16_kernel<<<1024, 256, 0, stream>>>(W, Wbf, (int)nW);
    cvt_bf16_kernel<<<96, 256, 0, stream>>>(Wy, Wybf, (int)nWy);
    cvt_bf16_kernel<<<256, 256, 0, stream>>>(Ua, Uabf, (int)nUa);
  }

  hipFuncSetAttribute((const void*)lstm_attn_kernel<1>,
                      hipFuncAttributeMaxDynamicSharedMemorySize, SMEM_BYTES);
  hipFuncSetAttribute((const void*)lstm_attn_kernel<0>,
                      hipFuncAttributeMaxDynamicSharedMemorySize, SMEM_BYTES);

  if (usebf) {
    lstm_attn_kernel<1><<<NB, 512, SMEM_BYTES, stream>>>(
        H, y0, emb, Wa, Ua, ba, Va, W, U, bias, Wy, fcw, fcb, Ubf, Wbf, Wybf, Uabf, out);
  } else {
    lstm_attn_kernel<0><<<NB, 512, SMEM_BYTES, stream>>>(
        H, y0, emb, Wa, Ua, ba, Va, W, U, bias, Wy, fcw, fcb, Ubf, Wbf, Wybf, Uabf, out);
  }
}

// Round 6
// 852.501 us; speedup vs baseline: 2.2638x; 1.2216x over previous
//
#include <hip/hip_runtime.h>
#include <hip/hip_fp8.h>
#include <cstdint>
#include <cstddef>

// Problem dims (TemporalLSTM_77455440216810)
// r6: back to 2 b/WG (1024 thr, 1 WG/CU) so both b's SHARE one L2 weight
// stream, but gate GEMM moved onto f16 MFMA (M=2 batches the two b's in
// A rows 0/1). Weights pre-repacked into f16 B-frag layout by one repack
// kernel (replaces the 4 bf16 cvt kernels). r5 showed the GEMV unpack on
// the VALU pipe was the dominant cost (VALUBusy 54.5%, MfmaUtil 4.7%).
#define IDIM 128   // INPUT_DIM
#define HS   256   // HIDDEN
#define SEQL 512   // SEQ
#define TOUT 24    // OUT (scan steps)
#define TMP  64    // TEMP
#define NB   512   // B
#define G4   1024  // 4*HS

typedef unsigned short u16;
typedef unsigned int   u32;
typedef __attribute__((ext_vector_type(4))) float f32x4;     // MFMA C/D frag
typedef _Float16 f16x8 __attribute__((ext_vector_type(8)));  // f16 MFMA A/B frag

// ---- LDS layout (bytes). TWO batch elements per WG. Total 163280 <= 163840.
#define OFF_HFRAG 0        // 131072: 2 x (512x128 fp8) MFMA-A frags
#define OFF_GATEP 131072   // 16384: WBF=1: gates f32[2][1024] (8KB)
                           //        WBF=0: gate partials u32[2][4][512]
                           //        UNION Wa fp8 B-frags (8192) -- disjoint phases
#define OFF_E     147456   // 4096: e[2][512] f32
#define OFF_CUAP  151552   // 2048: cua partials [2][4][64] f32
#define OFF_CTXP  153600   // 2048: ctx partials [2][2][128] f32
#define OFF_H     155648   // 2048: h[2][256] f32
#define OFF_C     157696   // 2048: c[2][256] f32
#define OFF_CTX   159744   // 1024: ctx[2][128] f32
#define OFF_CUABA 160768   // 512:  cua+ba [2][64] f32
#define OFF_VA    161280   // 256:  Va_t [64] f32
#define OFF_RED   161536   // 192:  reduction scratch [2][24] f32
#define OFF_Y     161728   // 8
#define OFF_INVD  161736   // 8
#define OFF_AB    161744   // 1536: packed f16 [ctx|h] pairs u32[2][192]
#define SMEM_BYTES 163280

__device__ __forceinline__ u16 f2bf(float f) {            // RNE f32->bf16
  union { float f; u32 u; } v; v.f = f;
  u32 r = v.u + 0x7FFFu + ((v.u >> 16) & 1u);
  return (u16)(r >> 16);
}
__device__ __forceinline__ float bflo(u32 u) {
  union { u32 u; float f; } v; v.u = u << 16; return v.f;
}
__device__ __forceinline__ float bfhi(u32 u) {
  union { u32 u; float f; } v; v.u = u & 0xFFFF0000u; return v.f;
}
__device__ __forceinline__ u32 pkbf(float a, float b) {
  return (u32)f2bf(a) | ((u32)f2bf(b) << 16);
}
__device__ __forceinline__ u32 pkf16(float a, float b) {  // 2 x f32 -> packed f16 (RNE)
  union { _Float16 h[2]; u32 u; } v;
  v.h[0] = (_Float16)a; v.h[1] = (_Float16)b; return v.u;
}
// fp8 e4m3 (OCP) pack/unpack
__device__ __forceinline__ u32 pk4_fp8(float a, float b, float c, float d) {
#if __has_builtin(__builtin_amdgcn_cvt_pk_fp8_f32)
  u32 v = (u32)__builtin_amdgcn_cvt_pk_fp8_f32(a, b, 0, false);
  v = (u32)__builtin_amdgcn_cvt_pk_fp8_f32(c, d, (int)v, true);
  return v;
#else
  __hip_fp8_e4m3 x(a), y(b), z(c), w(d);
  return (u32)x.__x | ((u32)y.__x << 8) | ((u32)z.__x << 16) | ((u32)w.__x << 24);
#endif
}
template <int S>
__device__ __forceinline__ float fp8_f32(u32 v) {
#if __has_builtin(__builtin_amdgcn_cvt_f32_fp8)
  return __builtin_amdgcn_cvt_f32_fp8((int)v, S);
#else
  __hip_fp8_e4m3 x; x.__x = (unsigned char)(v >> (8 * S)); return (float)x;
#endif
}
// Pade(3/2) tanh for attention scores (error attenuated by Va-dot + /16 + softmax)
__device__ __forceinline__ float tanh_fast(float x) {
  float x2 = x * x;
  float r = x * (27.0f + x2) * __builtin_amdgcn_rcpf(27.0f + 9.0f * x2);
  return fminf(fmaxf(r, -1.0f), 1.0f);
}
__device__ __forceinline__ float sigmoid_acc(float x) {
  return __builtin_amdgcn_rcpf(1.0f + __builtin_exp2f(-1.4426950408889634f * x));
}
__device__ __forceinline__ float tanh_acc(float x) {
  return 1.0f - 2.0f * __builtin_amdgcn_rcpf(1.0f + __builtin_exp2f(2.8853900817779268f * x));
}

// Repack W[128][24][1024] + U[256][24][1024] (f32) into f16 MFMA-B frags:
// frag f = ((t*64 + nt)*12 + kc)*64 + lane holds 8 f16: n = nt*16+(lane&15),
// k = kc*32 + (lane>>4)*8 + j;  k<128 -> W[k], else U[k-128].
__global__ void repack_f16_kernel(const float* __restrict__ W, const float* __restrict__ U,
                                  u32* __restrict__ WUf) {
  int f = blockIdx.x * blockDim.x + threadIdx.x;   // 0..1179647
  if (f >= TOUT * 64 * 12 * 64) return;
  int lane = f & 63;
  int kc = (f >> 6) % 12;
  int nt = (f / (64 * 12)) % 64;
  int t = f / (64 * 12 * 64);
  int lm = lane & 15, q = lane >> 4;
  int n = nt * 16 + lm;
  int kb = kc * 32 + q * 8;
  u32 w4[4];
#pragma unroll
  for (int jj = 0; jj < 4; ++jj) {
    int k0 = kb + 2 * jj, k1 = k0 + 1;
    float v0 = (k0 < 128) ? W[((size_t)k0 * TOUT + t) * G4 + n]
                          : U[((size_t)(k0 - 128) * TOUT + t) * G4 + n];
    float v1 = (k1 < 128) ? W[((size_t)k1 * TOUT + t) * G4 + n]
                          : U[((size_t)(k1 - 128) * TOUT + t) * G4 + n];
    w4[jj] = pkf16(v0, v1);
  }
  *(uint4*)(WUf + (size_t)f * 4) = make_uint4(w4[0], w4[1], w4[2], w4[3]);
}

// Persistent kernel: one WG (1024 thr) = TWO batch elements, all 24 steps.
// 256 WGs -> 1 WG/CU (163 KB LDS). Gate GEMM on f16 MFMA, M=2 = both b's.
template <int WBF>
__global__ __launch_bounds__(1024, 4) void lstm_attn_kernel(
    const float* __restrict__ H, const float* __restrict__ y0, const float* __restrict__ emb,
    const float* __restrict__ Wa, const float* __restrict__ UaF, const float* __restrict__ ba,
    const float* __restrict__ Va, const float* __restrict__ WF, const float* __restrict__ UF,
    const float* __restrict__ bias, const float* __restrict__ WyF, const float* __restrict__ fcw,
    const float* __restrict__ fcb, const u32* __restrict__ WUf, float* __restrict__ out) {
  const int bg0 = blockIdx.x * 2;
  const int tid = threadIdx.x;
  const int lane = tid & 63;
  const int wv = tid >> 6;  // 0..15
  extern __shared__ char smem[];
  float* eL     = (float*)(smem + OFF_E);
  float* hL     = (float*)(smem + OFF_H);
  float* cL     = (float*)(smem + OFF_C);
  float* ctxL   = (float*)(smem + OFF_CTX);
  float* cuapL  = (float*)(smem + OFF_CUAP);
  float* ctxpL  = (float*)(smem + OFF_CTXP);
  float* cuabaL = (float*)(smem + OFF_CUABA);
  float* vaL    = (float*)(smem + OFF_VA);
  float* redL   = (float*)(smem + OFF_RED);
  float* yL     = (float*)(smem + OFF_Y);
  float* invdL  = (float*)(smem + OFF_INVD);
  u32* gatepU   = (u32*)(smem + OFF_GATEP);
  float* gatesF = (float*)(smem + OFF_GATEP);
  u32* abU      = (u32*)(smem + OFF_AB);

  // ---- one-time: stage H for both b's into LDS as fp8 MFMA-A fragments ----
  // A-frag (16x16x32 family): m = lane&15, k = (lane>>4)*8 + j.
#pragma unroll 2
  for (int it = 0; it < 16; ++it) {
    int ch = it * 1024 + tid;           // 0..16383
    int bl = ch >> 13;                  // which b
    int c2 = ch & 8191;
    int l = c2 >> 4, oct = c2 & 15;
    const float* src = H + (size_t)(bg0 + bl) * (SEQL * IDIM) + l * IDIM + oct * 8;
    float4 a = *(const float4*)src;
    float4 c4 = *(const float4*)(src + 4);
    u32 lo = pk4_fp8(a.x, a.y, a.z, a.w);
    u32 hi = pk4_fp8(c4.x, c4.y, c4.z, c4.w);
    int mtile = l >> 4, lm = l & 15, kc = oct >> 2, q = oct & 3;
    *(uint2*)(smem + OFF_HFRAG + (size_t)bl * 65536 +
              (size_t)(((mtile * 4 + kc) * 64 + q * 16 + lm)) * 8) = make_uint2(lo, hi);
  }
  if (tid < 512) {  // carries
    int b = tid >> 8, i = tid & 255;
    hL[b * 256 + i] = emb[(size_t)(bg0 + b) * 512 + i];
    cL[b * 256 + i] = emb[(size_t)(bg0 + b) * 512 + 256 + i];
  }
  if (tid < 256) {  // initial packed-f16 h (A-operand rows for P4 MFMA)
    int b = tid >> 7, i = tid & 127;
    const float* hp = emb + (size_t)(bg0 + b) * 512 + 2 * i;
    abU[b * 192 + 64 + i] = pkf16(hp[0], hp[1]);
  }
  if (tid < 2) yL[tid] = y0[bg0 + tid];
  __syncthreads();

#pragma unroll 1
  for (int t = 0; t < TOUT; ++t) {
    // ===== P0: stage Wa_t fp8 B-frags (union w/ gatesF) + c@Ua partials =====
    {  // B-frag: n = lane&15, k = (lane>>4)*8+j; frag (nt,kc) at ((nt*4+kc)*64+lane)*8
      int nt = tid >> 8, kc = (tid >> 6) & 3, l6 = tid & 63;
      int lm = l6 & 15, q = l6 >> 4;
      int n = nt * 16 + lm;
      float f[8];
#pragma unroll
      for (int j = 0; j < 8; ++j) {
        int k = kc * 32 + q * 8 + j;
        f[j] = Wa[((size_t)k * TOUT + t) * TMP + n];
      }
      *(uint2*)(smem + OFF_GATEP + (size_t)tid * 8) =
          make_uint2(pk4_fp8(f[0], f[1], f[2], f[3]), pk4_fp8(f[4], f[5], f[6], f[7]));
    }
    if (tid < 128) {  // cUa partials (f32 Ua): both b's, 4 d-parts
      int j2 = tid & 31, part = tid >> 5;
      float s00 = 0.f, s01 = 0.f, s10 = 0.f, s11 = 0.f;
#pragma unroll 8
      for (int i = 0; i < 64; ++i) {
        int d = part * 64 + i;
        const float* up = UaF + ((size_t)d * TOUT + t) * TMP + j2 * 2;
        float u0 = up[0], u1 = up[1];
        float c0 = cL[d], c1 = cL[256 + d];
        s00 += c0 * u0; s01 += c0 * u1;
        s10 += c1 * u0; s11 += c1 * u1;
      }
      cuapL[(0 * 4 + part) * 64 + j2 * 2] = s00;
      cuapL[(0 * 4 + part) * 64 + j2 * 2 + 1] = s01;
      cuapL[(1 * 4 + part) * 64 + j2 * 2] = s10;
      cuapL[(1 * 4 + part) * 64 + j2 * 2 + 1] = s11;
    }
    __syncthreads();
    if (tid < 128) {
      int b = tid >> 6, j = tid & 63;
      float s = 0.f;
#pragma unroll
      for (int p = 0; p < 4; ++p) s += cuapL[(b * 4 + p) * 64 + j];
      cuabaL[b * 64 + j] = s + ba[t * TMP + j];
      if (tid < 64) vaL[j] = Va[j * TOUT + t];
    }
    __syncthreads();

    // ===== P1: e-pass  T = H_b @ Wa_t (fp8 MFMA), tanh, Va-dot =====
    {
      const int b = wv >> 3, m8 = wv & 7;
      const int lm = lane & 15, q = lane >> 4;
      float cb[4], vv[4];
#pragma unroll
      for (int nt = 0; nt < 4; ++nt) {
        cb[nt] = cuabaL[b * 64 + nt * 16 + lm];
        vv[nt] = vaL[nt * 16 + lm];
      }
      long bfr[4][4];
#pragma unroll
      for (int nt = 0; nt < 4; ++nt)
#pragma unroll
        for (int kc = 0; kc < 4; ++kc)
          bfr[nt][kc] = *(const long*)(smem + OFF_GATEP + (size_t)(((nt * 4 + kc) * 64 + lane)) * 8);
#pragma unroll
      for (int mm = 0; mm < 4; ++mm) {
        int mtile = m8 * 4 + mm;
        f32x4 acc0 = 0, acc1 = 0, acc2 = 0, acc3 = 0;
#pragma unroll
        for (int kc = 0; kc < 4; ++kc) {
          long af = *(const long*)(smem + OFF_HFRAG + (size_t)b * 65536 +
                                   (size_t)(((mtile * 4 + kc) * 64 + lane)) * 8);
          acc0 = __builtin_amdgcn_mfma_f32_16x16x32_fp8_fp8(af, bfr[0][kc], acc0, 0, 0, 0);
          acc1 = __builtin_amdgcn_mfma_f32_16x16x32_fp8_fp8(af, bfr[1][kc], acc1, 0, 0, 0);
          acc2 = __builtin_amdgcn_mfma_f32_16x16x32_fp8_fp8(af, bfr[2][kc], acc2, 0, 0, 0);
          acc3 = __builtin_amdgcn_mfma_f32_16x16x32_fp8_fp8(af, bfr[3][kc], acc3, 0, 0, 0);
        }
        // C/D: col = nt*16 + (lane&15), row = mtile*16 + (lane>>4)*4 + r
#pragma unroll
        for (int r = 0; r < 4; ++r) {
          float v = tanh_fast(acc0[r] + cb[0]) * vv[0] + tanh_fast(acc1[r] + cb[1]) * vv[1] +
                    tanh_fast(acc2[r] + cb[2]) * vv[2] + tanh_fast(acc3[r] + cb[3]) * vv[3];
          v += __shfl_xor(v, 1);
          v += __shfl_xor(v, 2);
          v += __shfl_xor(v, 4);
          v += __shfl_xor(v, 8);
          if (lm == 0) eL[b * 512 + mtile * 16 + q * 4 + r] = v;
        }
      }
    }
    __syncthreads();

    // ===== P2: per-b softmax (logits = e/16) =====
    {
      int b = tid >> 9;
      int w8 = (tid >> 6) & 7;
      float v = eL[tid];
      float m = v;
#pragma unroll
      for (int msk = 1; msk <= 32; msk <<= 1) m = fmaxf(m, __shfl_xor(m, msk));
      if (lane == 0) redL[b * 24 + w8] = m;
      __syncthreads();
      float M = redL[b * 24];
#pragma unroll
      for (int p = 1; p < 8; ++p) M = fmaxf(M, redL[b * 24 + p]);
      float pv = __builtin_exp2f((v - M) * 0.0901684400347379f);  // (1/16)*log2(e)
      eL[tid] = pv;
      float s = pv;
#pragma unroll
      for (int msk = 1; msk <= 32; msk <<= 1) s += __shfl_xor(s, msk);
      if (lane == 0) redL[b * 24 + 8 + w8] = s;
      __syncthreads();
      if ((tid & 511) == 0) {
        int b2 = tid >> 9;
        float den = 0.f;
#pragma unroll
        for (int p = 0; p < 8; ++p) den += redL[b2 * 24 + 8 + p];
        invdL[b2] = __builtin_amdgcn_rcpf(den);
      }
    }

    // ===== P3: ctx_d = sum_l p_l H[l][d] (fp8 H from LDS) =====
    {
      int b = tid >> 9, stid = tid & 511;
      int lsub = stid & 15, dch = (stid >> 4) & 15, half = stid >> 8;
      int kc = dch >> 2, q = dch & 3;
      const char* hbase = smem + OFF_HFRAG + (size_t)b * 65536;
      float a[8] = {0.f, 0.f, 0.f, 0.f, 0.f, 0.f, 0.f, 0.f};
#pragma unroll 4
      for (int i = 0; i < 16; ++i) {
        int mt = half * 16 + i;
        int l = mt * 16 + lsub;
        uint2 hv = *(const uint2*)(hbase + (size_t)(((mt * 4 + kc) * 64 + q * 16 + lsub)) * 8);
        float p = eL[b * 512 + l];
        a[0] += p * fp8_f32<0>(hv.x); a[1] += p * fp8_f32<1>(hv.x);
        a[2] += p * fp8_f32<2>(hv.x); a[3] += p * fp8_f32<3>(hv.x);
        a[4] += p * fp8_f32<0>(hv.y); a[5] += p * fp8_f32<1>(hv.y);
        a[6] += p * fp8_f32<2>(hv.y); a[7] += p * fp8_f32<3>(hv.y);
      }
#pragma unroll
      for (int msk = 1; msk <= 8; msk <<= 1)
#pragma unroll
        for (int j = 0; j < 8; ++j) a[j] += __shfl_xor(a[j], msk);
      if (lsub == 0) {
        float* dst = &ctxpL[b * 256 + half * 128 + dch * 8];
#pragma unroll
        for (int j = 0; j < 8; ++j) dst[j] = a[j];
      }
    }
    __syncthreads();
    if (tid < 256) {
      int b = tid >> 7, d = tid & 127;
      float v = (ctxpL[b * 256 + d] + ctxpL[b * 256 + 128 + d]) * invdL[b];
      ctxL[b * 128 + d] = v;
      float vo = __shfl_xor(v, 1);               // pack f16 pairs for P4 A-frags
      if (!(d & 1)) abU[b * 192 + (d >> 1)] = pkf16(v, vo);
    }
    __syncthreads();

    // ===== P4: gates = [ctx|h] @ [W;U] =====
    if (WBF) {
      // f16 MFMA, M=2 (A row0 = b0, row1 = b1; rows 2..15 don't-care).
      // Per wave: 4 nt tiles x 12 kc. B-frags stream from WUf (global/L2),
      // SHARED across both b's -> one 786KB stream per CU per step.
      const int q = lane >> 4;
      const char* abase = smem + OFF_AB + (size_t)(lane & 1) * 768;
      const f16x8* wb = reinterpret_cast<const f16x8*>(WUf) +
                        ((size_t)t * 64 + wv * 4) * 12 * 64 + lane;
      f32x4 acc0 = 0, acc1 = 0, acc2 = 0, acc3 = 0;
#pragma unroll 4
      for (int kc = 0; kc < 12; ++kc) {
        f16x8 a = *(const f16x8*)(abase + kc * 64 + q * 16);
        const f16x8* bp = wb + (size_t)kc * 64;
        acc0 = __builtin_amdgcn_mfma_f32_16x16x32_f16(a, bp[0], acc0, 0, 0, 0);
        acc1 = __builtin_amdgcn_mfma_f32_16x16x32_f16(a, bp[12 * 64], acc1, 0, 0, 0);
        acc2 = __builtin_amdgcn_mfma_f32_16x16x32_f16(a, bp[2 * 12 * 64], acc2, 0, 0, 0);
        acc3 = __builtin_amdgcn_mfma_f32_16x16x32_f16(a, bp[3 * 12 * 64], acc3, 0, 0, 0);
      }
      // D: col = nt*16 + (lane&15); row 0 -> acc[0] (b0), row 1 -> acc[1] (b1)
      if (lane < 16) {
        int c0 = wv * 64 + lane;
        gatesF[c0]      = acc0[0];  gatesF[1024 + c0]      = acc0[1];
        gatesF[c0 + 16] = acc1[0];  gatesF[1024 + c0 + 16] = acc1[1];
        gatesF[c0 + 32] = acc2[0];  gatesF[1024 + c0 + 32] = acc2[1];
        gatesF[c0 + 48] = acc3[0];  gatesF[1024 + c0 + 48] = acc3[1];
      }
    } else {
      // Fallback: f32 GEMV, each weight dword used for both b's.
      int gc = tid & 255, dpart = tid >> 8;
      const int c0 = gc * 4;
      float g0[4] = {0.f, 0.f, 0.f, 0.f};
      float g1[4] = {0.f, 0.f, 0.f, 0.f};
      {
        const float* wpf = WF + ((size_t)(dpart * 32) * TOUT + t) * G4 + c0;
#pragma unroll 2
        for (int i4 = 0; i4 < 8; ++i4) {
          float4 cv0 = *(const float4*)&ctxL[dpart * 32 + i4 * 4];
          float4 cv1 = *(const float4*)&ctxL[128 + dpart * 32 + i4 * 4];
#pragma unroll
          for (int j4 = 0; j4 < 4; ++j4) {
            float4 wf = *(const float4*)wpf;
            wpf += (size_t)TOUT * G4;
            float cc0 = (j4 == 0) ? cv0.x : (j4 == 1) ? cv0.y : (j4 == 2) ? cv0.z : cv0.w;
            float cc1 = (j4 == 0) ? cv1.x : (j4 == 1) ? cv1.y : (j4 == 2) ? cv1.z : cv1.w;
            g0[0] += cc0 * wf.x; g0[1] += cc0 * wf.y; g0[2] += cc0 * wf.z; g0[3] += cc0 * wf.w;
            g1[0] += cc1 * wf.x; g1[1] += cc1 * wf.y; g1[2] += cc1 * wf.z; g1[3] += cc1 * wf.w;
          }
        }
      }
      {
        const float* upf = UF + ((size_t)(dpart * 64) * TOUT + t) * G4 + c0;
#pragma unroll 2
        for (int i4 = 0; i4 < 16; ++i4) {
          float4 hv0 = *(const float4*)&hL[dpart * 64 + i4 * 4];
          float4 hv1 = *(const float4*)&hL[256 + dpart * 64 + i4 * 4];
#pragma unroll
          for (int j4 = 0; j4 < 4; ++j4) {
            float4 wf = *(const float4*)upf;
            upf += (size_t)TOUT * G4;
            float hh0 = (j4 == 0) ? hv0.x : (j4 == 1) ? hv0.y : (j4 == 2) ? hv0.z : hv0.w;
            float hh1 = (j4 == 0) ? hv1.x : (j4 == 1) ? hv1.y : (j4 == 2) ? hv1.z : hv1.w;
            g0[0] += hh0 * wf.x; g0[1] += hh0 * wf.y; g0[2] += hh0 * wf.z; g0[3] += hh0 * wf.w;
            g1[0] += hh1 * wf.x; g1[1] += hh1 * wf.y; g1[2] += hh1 * wf.z; g1[3] += hh1 * wf.w;
          }
        }
      }
      *(uint2*)&gatepU[((0 * 4 + dpart) * 512) + gc * 2] =
          make_uint2(pkbf(g0[0], g0[1]), pkbf(g0[2], g0[3]));
      *(uint2*)&gatepU[((1 * 4 + dpart) * 512) + gc * 2] =
          make_uint2(pkbf(g1[0], g1[1]), pkbf(g1[2], g1[3]));
    }
    __syncthreads();

    // ===== P5: LSTM cell + y =====
    float ypart = 0.f;
    int bh = tid >> 8, hc = tid & 255;
    if (tid < 512) {
      float yprev = yL[bh];
      float gv[4];
#pragma unroll
      for (int gi = 0; gi < 4; ++gi) {
        int col = gi * 256 + hc;
        float s;
        if (WBF) {
          s = gatesF[bh * 1024 + col];
        } else {
          int ci = col >> 1, sel = col & 1;
          s = 0.f;
#pragma unroll
          for (int p = 0; p < 4; ++p) {
            u32 u = gatepU[(bh * 4 + p) * 512 + ci];
            s += sel ? bfhi(u) : bflo(u);
          }
        }
        s += bias[(size_t)t * G4 + col];
        gv[gi] = s + yprev * WyF[t * G4 + col];
      }
      float ig = sigmoid_acc(gv[0]);
      float fg = sigmoid_acc(gv[1]);
      float gg = tanh_acc(gv[2]);
      float og = sigmoid_acc(gv[3]);
      float cn = fg * cL[bh * 256 + hc] + ig * gg;
      float hn = og * tanh_acc(cn);
      cL[bh * 256 + hc] = cn;
      hL[bh * 256 + hc] = hn;
      out[12288 + ((size_t)(bg0 + bh) * TOUT + t) * HS + hc] = hn;
      ypart = hn * fcw[t * HS + hc];
      float hho = __shfl_xor(hn, 1);             // pack f16 pairs for next P4
      if (!(hc & 1)) abU[bh * 192 + 64 + (hc >> 1)] = pkf16(hn, hho);
    }
#pragma unroll
    for (int msk = 1; msk <= 32; msk <<= 1) ypart += __shfl_xor(ypart, msk);
    if (tid < 512 && lane == 0) redL[bh * 24 + 16 + ((tid >> 6) & 3)] = ypart;
    __syncthreads();
    if (tid == 0 || tid == 512) {
      int b2 = tid >> 9;
      float y = redL[b2 * 24 + 16] + redL[b2 * 24 + 17] + redL[b2 * 24 + 18] +
                redL[b2 * 24 + 19] + fcb[t];
      yL[b2] = y;
      out[(size_t)(bg0 + b2) * TOUT + t] = y;
    }
    __syncthreads();
  }
}

extern "C" void kernel_launch(void* const* d_in, const int* in_sizes, int n_in, void* d_out,
                              int out_size, void* d_ws, size_t ws_size, hipStream_t stream) {
  const float* H    = (const float*)d_in[0];
  const float* y0   = (const float*)d_in[1];
  const float* emb  = (const float*)d_in[2];
  const float* Wa   = (const float*)d_in[3];
  const float* Ua   = (const float*)d_in[4];
  const float* ba   = (const float*)d_in[5];
  const float* Va   = (const float*)d_in[6];
  const float* W    = (const float*)d_in[7];
  const float* U    = (const float*)d_in[8];
  const float* bias = (const float*)d_in[9];
  const float* Wy   = (const float*)d_in[10];
  const float* fcw  = (const float*)d_in[11];
  const float* fcb  = (const float*)d_in[12];
  float* out = (float*)d_out;

  const size_t nFrag = (size_t)TOUT * 64 * 12 * 64;   // 1,179,648 frags x 16B
  const size_t need = nFrag * 16;                     // 18,874,368 B
  const bool usebf = (d_ws != nullptr) && (ws_size >= need);
  u32* WUf = (u32*)d_ws;

  if (usebf) {
    repack_f16_kernel<<<(int)(nFrag / 256), 256, 0, stream>>>(W, U, WUf);
  }

  hipFuncSetAttribute((const void*)lstm_attn_kernel<1>,
                      hipFuncAttributeMaxDynamicSharedMemorySize, SMEM_BYTES);
  hipFuncSetAttribute((const void*)lstm_attn_kernel<0>,
                      hipFuncAttributeMaxDynamicSharedMemorySize, SMEM_BYTES);

  if (usebf) {
    lstm_attn_kernel<1><<<NB / 2, 1024, SMEM_BYTES, stream>>>(
        H, y0, emb, Wa, Ua, ba, Va, W, U, bias, Wy, fcw, fcb, WUf, out);
  } else {
    lstm_attn_kernel<0><<<NB / 2, 1024, SMEM_BYTES, stream>>>(
        H, y0, emb, Wa, Ua, ba, Va, W, U, bias, Wy, fcw, fcb, WUf, out);
  }
}

// Round 7
// 795.927 us; speedup vs baseline: 2.4247x; 1.0711x over previous
//
#include <hip/hip_runtime.h>
#include <hip/hip_fp8.h>
#include <cstdint>
#include <cstddef>

// Problem dims (TemporalLSTM_77455440216810)
// r7: r6 (MFMA gates) split into TWO 512-thr WGs/CU, ONE b each -> two
// independent barrier domains per CU fill each other's latency stalls.
// r5 showed desync costs nothing when the duplicated work is small; r6
// moved the gate GEMV onto MFMA so the only duplication left is the L2
// weight stream (5x headroom measured: 6.8 vs 34.5 TB/s).
#define IDIM 128   // INPUT_DIM
#define HS   256   // HIDDEN
#define SEQL 512   // SEQ
#define TOUT 24    // OUT (scan steps)
#define TMP  64    // TEMP
#define NB   512   // B
#define G4   1024  // 4*HS

typedef unsigned short u16;
typedef unsigned int   u32;
typedef __attribute__((ext_vector_type(4))) float f32x4;     // MFMA C/D frag
typedef _Float16 f16x8 __attribute__((ext_vector_type(8)));  // f16 MFMA A/B frag

// ---- LDS layout (bytes). ONE batch element per 512-thr WG. Total 81768;
// ---- 2 x 81768 = 163536 <= 163840 -> 2 WGs/CU.
#define OFF_HFRAG 0        // 65536: 512x128 fp8 MFMA-A frags
#define OFF_GATEP 65536    // 8192: Wa fp8 B-frags UNION gates f32[1024] (4KB)
                           //       UNION (WBF=0) gate partials u32[2][512]
#define OFF_E     73728    // 2048: e[512] f32
#define OFF_CUAP  75776    // 2048: cua partials [8][64] f32
                           //       UNION ctx partials [2][128] f32
#define OFF_H     77824    // 1024: h[256] f32
#define OFF_C     78848    // 1024: c[256] f32
#define OFF_CTX   79872    // 512:  ctx[128] f32
#define OFF_CUABA 80384    // 256:  cua+ba [64] f32
#define OFF_VA    80640    // 256:  Va_t [64] f32
#define OFF_RED   80896    // 96:   reduction scratch [24] f32
#define OFF_Y     80992    // 4
#define OFF_INVD  80996    // 4
#define OFF_AB    81000    // 768:  packed f16 [ctx(64)|h(128)] pairs u32[192]
#define SMEM_BYTES 81768

__device__ __forceinline__ u16 f2bf(float f) {            // RNE f32->bf16
  union { float f; u32 u; } v; v.f = f;
  u32 r = v.u + 0x7FFFu + ((v.u >> 16) & 1u);
  return (u16)(r >> 16);
}
__device__ __forceinline__ float bflo(u32 u) {
  union { u32 u; float f; } v; v.u = u << 16; return v.f;
}
__device__ __forceinline__ float bfhi(u32 u) {
  union { u32 u; float f; } v; v.u = u & 0xFFFF0000u; return v.f;
}
__device__ __forceinline__ u32 pkbf(float a, float b) {
  return (u32)f2bf(a) | ((u32)f2bf(b) << 16);
}
__device__ __forceinline__ u32 pkf16(float a, float b) {  // 2 x f32 -> packed f16 (RNE)
  union { _Float16 h[2]; u32 u; } v;
  v.h[0] = (_Float16)a; v.h[1] = (_Float16)b; return v.u;
}
// fp8 e4m3 (OCP) pack/unpack
__device__ __forceinline__ u32 pk4_fp8(float a, float b, float c, float d) {
#if __has_builtin(__builtin_amdgcn_cvt_pk_fp8_f32)
  u32 v = (u32)__builtin_amdgcn_cvt_pk_fp8_f32(a, b, 0, false);
  v = (u32)__builtin_amdgcn_cvt_pk_fp8_f32(c, d, (int)v, true);
  return v;
#else
  __hip_fp8_e4m3 x(a), y(b), z(c), w(d);
  return (u32)x.__x | ((u32)y.__x << 8) | ((u32)z.__x << 16) | ((u32)w.__x << 24);
#endif
}
template <int S>
__device__ __forceinline__ float fp8_f32(u32 v) {
#if __has_builtin(__builtin_amdgcn_cvt_f32_fp8)
  return __builtin_amdgcn_cvt_f32_fp8((int)v, S);
#else
  __hip_fp8_e4m3 x; x.__x = (unsigned char)(v >> (8 * S)); return (float)x;
#endif
}
// Pade(3/2) tanh for attention scores (error attenuated by Va-dot + /16 + softmax)
__device__ __forceinline__ float tanh_fast(float x) {
  float x2 = x * x;
  float r = x * (27.0f + x2) * __builtin_amdgcn_rcpf(27.0f + 9.0f * x2);
  return fminf(fmaxf(r, -1.0f), 1.0f);
}
__device__ __forceinline__ float sigmoid_acc(float x) {
  return __builtin_amdgcn_rcpf(1.0f + __builtin_exp2f(-1.4426950408889634f * x));
}
__device__ __forceinline__ float tanh_acc(float x) {
  return 1.0f - 2.0f * __builtin_amdgcn_rcpf(1.0f + __builtin_exp2f(2.8853900817779268f * x));
}

// Repack W[128][24][1024] + U[256][24][1024] (f32) into f16 MFMA-B frags:
// frag f = ((t*64 + nt)*12 + kc)*64 + lane holds 8 f16: n = nt*16+(lane&15),
// k = kc*32 + (lane>>4)*8 + j;  k<128 -> W[k], else U[k-128].
__global__ void repack_f16_kernel(const float* __restrict__ W, const float* __restrict__ U,
                                  u32* __restrict__ WUf) {
  int f = blockIdx.x * blockDim.x + threadIdx.x;   // 0..1179647
  if (f >= TOUT * 64 * 12 * 64) return;
  int lane = f & 63;
  int kc = (f >> 6) % 12;
  int nt = (f / (64 * 12)) % 64;
  int t = f / (64 * 12 * 64);
  int lm = lane & 15, q = lane >> 4;
  int n = nt * 16 + lm;
  int kb = kc * 32 + q * 8;
  u32 w4[4];
#pragma unroll
  for (int jj = 0; jj < 4; ++jj) {
    int k0 = kb + 2 * jj, k1 = k0 + 1;
    float v0 = (k0 < 128) ? W[((size_t)k0 * TOUT + t) * G4 + n]
                          : U[((size_t)(k0 - 128) * TOUT + t) * G4 + n];
    float v1 = (k1 < 128) ? W[((size_t)k1 * TOUT + t) * G4 + n]
                          : U[((size_t)(k1 - 128) * TOUT + t) * G4 + n];
    w4[jj] = pkf16(v0, v1);
  }
  *(uint4*)(WUf + (size_t)f * 4) = make_uint4(w4[0], w4[1], w4[2], w4[3]);
}

// Persistent kernel: one WG (512 thr) = ONE batch element, all 24 steps.
// 512 WGs -> 2 WGs/CU. Gate GEMM on f16 MFMA (D row 0 used; A rows are
// broadcast copies of [ctx|h]).
template <int WBF>
__global__ __launch_bounds__(512, 4) void lstm_attn_kernel(
    const float* __restrict__ H, const float* __restrict__ y0, const float* __restrict__ emb,
    const float* __restrict__ Wa, const float* __restrict__ UaF, const float* __restrict__ ba,
    const float* __restrict__ Va, const float* __restrict__ WF, const float* __restrict__ UF,
    const float* __restrict__ bias, const float* __restrict__ WyF, const float* __restrict__ fcw,
    const float* __restrict__ fcb, const u32* __restrict__ WUf, float* __restrict__ out) {
  const int bg = blockIdx.x;
  const int tid = threadIdx.x;        // 0..511
  const int lane = tid & 63;
  const int wv = tid >> 6;            // 0..7
  extern __shared__ char smem[];
  float* eL     = (float*)(smem + OFF_E);
  float* hL     = (float*)(smem + OFF_H);
  float* cL     = (float*)(smem + OFF_C);
  float* ctxL   = (float*)(smem + OFF_CTX);
  float* cuapL  = (float*)(smem + OFF_CUAP);
  float* ctxpL  = (float*)(smem + OFF_CUAP);   // union (disjoint phases)
  float* cuabaL = (float*)(smem + OFF_CUABA);
  float* vaL    = (float*)(smem + OFF_VA);
  float* redL   = (float*)(smem + OFF_RED);
  float* yL     = (float*)(smem + OFF_Y);
  float* invdL  = (float*)(smem + OFF_INVD);
  u32* gatepU   = (u32*)(smem + OFF_GATEP);
  float* gatesF = (float*)(smem + OFF_GATEP);
  u32* abU      = (u32*)(smem + OFF_AB);

  // ---- one-time: stage H for this b into LDS as fp8 MFMA-A fragments ----
  // A-frag (16x16x32 family): m = lane&15, k = (lane>>4)*8 + j.
#pragma unroll 2
  for (int it = 0; it < 16; ++it) {
    int ch = it * 512 + tid;            // 0..8191
    int l = ch >> 4, oct = ch & 15;
    const float* src = H + (size_t)bg * (SEQL * IDIM) + l * IDIM + oct * 8;
    float4 a = *(const float4*)src;
    float4 c4 = *(const float4*)(src + 4);
    u32 lo = pk4_fp8(a.x, a.y, a.z, a.w);
    u32 hi = pk4_fp8(c4.x, c4.y, c4.z, c4.w);
    int mtile = l >> 4, lm2 = l & 15, kc = oct >> 2, q = oct & 3;
    *(uint2*)(smem + OFF_HFRAG +
              (size_t)(((mtile * 4 + kc) * 64 + q * 16 + lm2)) * 8) = make_uint2(lo, hi);
  }
  if (tid < 256) {  // carry init
    hL[tid] = emb[(size_t)bg * 512 + tid];
    cL[tid] = emb[(size_t)bg * 512 + 256 + tid];
  }
  if (tid < 128) {  // initial packed-f16 h (A rows for P4 MFMA)
    const float* hp = emb + (size_t)bg * 512 + 2 * tid;
    abU[64 + tid] = pkf16(hp[0], hp[1]);
  }
  if (tid == 0) yL[0] = y0[bg];
  __syncthreads();

#pragma unroll 1
  for (int t = 0; t < TOUT; ++t) {
    // ===== P0: stage Wa_t fp8 B-frags (union w/ gates) + c@Ua partials =====
#pragma unroll
    for (int half = 0; half < 2; ++half) {
      int id = half * 512 + tid;        // 0..1023
      int nt = id >> 8, kc = (id >> 6) & 3, l6 = id & 63;
      int lm = l6 & 15, q = l6 >> 4;
      int n = nt * 16 + lm;
      float f[8];
#pragma unroll
      for (int j = 0; j < 8; ++j) {
        int k = kc * 32 + q * 8 + j;
        f[j] = Wa[((size_t)k * TOUT + t) * TMP + n];
      }
      *(uint2*)(smem + OFF_GATEP + (size_t)id * 8) =
          make_uint2(pk4_fp8(f[0], f[1], f[2], f[3]), pk4_fp8(f[4], f[5], f[6], f[7]));
    }
    if (tid < 256) {  // cUa partials (f32 Ua): 8 d-parts of 32
      int j2 = tid & 31, part = tid >> 5;
      float s0 = 0.f, s1 = 0.f;
#pragma unroll 8
      for (int i = 0; i < 32; ++i) {
        int d = part * 32 + i;
        const float* up = UaF + ((size_t)d * TOUT + t) * TMP + j2 * 2;
        float c0 = cL[d];
        s0 += c0 * up[0]; s1 += c0 * up[1];
      }
      cuapL[part * 64 + j2 * 2] = s0;
      cuapL[part * 64 + j2 * 2 + 1] = s1;
    }
    if (tid >= 448) vaL[tid - 448] = Va[(size_t)(tid - 448) * TOUT + t];
    __syncthreads();
    if (tid < 64) {
      float s = 0.f;
#pragma unroll
      for (int p = 0; p < 8; ++p) s += cuapL[p * 64 + tid];
      cuabaL[tid] = s + ba[t * TMP + tid];
    }
    __syncthreads();

    // ===== P1: e-pass  T = H_b @ Wa_t (fp8 MFMA), tanh, Va-dot =====
    {
      const int lm = lane & 15, q = lane >> 4;
      long bfr[4][4];
#pragma unroll
      for (int nt = 0; nt < 4; ++nt)
#pragma unroll
        for (int kc = 0; kc < 4; ++kc)
          bfr[nt][kc] = *(const long*)(smem + OFF_GATEP + (size_t)(((nt * 4 + kc) * 64 + lane)) * 8);
      float cb0 = cuabaL[0 * 16 + lm], cb1 = cuabaL[1 * 16 + lm];
      float cb2 = cuabaL[2 * 16 + lm], cb3 = cuabaL[3 * 16 + lm];
      float vv0 = vaL[0 * 16 + lm], vv1 = vaL[1 * 16 + lm];
      float vv2 = vaL[2 * 16 + lm], vv3 = vaL[3 * 16 + lm];
#pragma unroll
      for (int mm = 0; mm < 4; ++mm) {
        int mtile = wv * 4 + mm;        // 8 waves x 4 = 32 mtiles
        f32x4 acc0 = 0, acc1 = 0, acc2 = 0, acc3 = 0;
#pragma unroll
        for (int kc = 0; kc < 4; ++kc) {
          long af = *(const long*)(smem + OFF_HFRAG +
                                   (size_t)(((mtile * 4 + kc) * 64 + lane)) * 8);
          acc0 = __builtin_amdgcn_mfma_f32_16x16x32_fp8_fp8(af, bfr[0][kc], acc0, 0, 0, 0);
          acc1 = __builtin_amdgcn_mfma_f32_16x16x32_fp8_fp8(af, bfr[1][kc], acc1, 0, 0, 0);
          acc2 = __builtin_amdgcn_mfma_f32_16x16x32_fp8_fp8(af, bfr[2][kc], acc2, 0, 0, 0);
          acc3 = __builtin_amdgcn_mfma_f32_16x16x32_fp8_fp8(af, bfr[3][kc], acc3, 0, 0, 0);
        }
        // C/D: col = nt*16 + (lane&15), row = mtile*16 + (lane>>4)*4 + r
#pragma unroll
        for (int r = 0; r < 4; ++r) {
          float v = tanh_fast(acc0[r] + cb0) * vv0 + tanh_fast(acc1[r] + cb1) * vv1 +
                    tanh_fast(acc2[r] + cb2) * vv2 + tanh_fast(acc3[r] + cb3) * vv3;
          v += __shfl_xor(v, 1);
          v += __shfl_xor(v, 2);
          v += __shfl_xor(v, 4);
          v += __shfl_xor(v, 8);
          if (lm == 0) eL[mtile * 16 + q * 4 + r] = v;
        }
      }
    }
    __syncthreads();

    // ===== P2: softmax over 512 (logits = e/16), all 8 waves =====
    {
      float v = eL[tid];
      float m = v;
#pragma unroll
      for (int msk = 1; msk <= 32; msk <<= 1) m = fmaxf(m, __shfl_xor(m, msk));
      if (lane == 0) redL[wv] = m;
      __syncthreads();
      float M = redL[0];
#pragma unroll
      for (int p = 1; p < 8; ++p) M = fmaxf(M, redL[p]);
      float pv = __builtin_exp2f((v - M) * 0.0901684400347379f);  // (1/16)*log2(e)
      eL[tid] = pv;
      float s = pv;
#pragma unroll
      for (int msk = 1; msk <= 32; msk <<= 1) s += __shfl_xor(s, msk);
      if (lane == 0) redL[8 + wv] = s;
      __syncthreads();
      if (tid == 0) {
        float den = redL[8] + redL[9] + redL[10] + redL[11] +
                    redL[12] + redL[13] + redL[14] + redL[15];
        invdL[0] = __builtin_amdgcn_rcpf(den);
      }
    }

    // ===== P3: ctx_d = sum_l p_l H[l][d] (fp8 H from LDS), 2 halves =====
    {
      int lsub = tid & 15, dch = (tid >> 4) & 15, half = tid >> 8;  // half 0..1
      int kc = dch >> 2, q2 = dch & 3;
      const char* hbase = smem + OFF_HFRAG;
      float a[8] = {0.f, 0.f, 0.f, 0.f, 0.f, 0.f, 0.f, 0.f};
#pragma unroll 4
      for (int i = 0; i < 16; ++i) {
        int mt = half * 16 + i;
        uint2 hv = *(const uint2*)(hbase + (size_t)(((mt * 4 + kc) * 64 + q2 * 16 + lsub)) * 8);
        float p = eL[mt * 16 + lsub];
        a[0] += p * fp8_f32<0>(hv.x); a[1] += p * fp8_f32<1>(hv.x);
        a[2] += p * fp8_f32<2>(hv.x); a[3] += p * fp8_f32<3>(hv.x);
        a[4] += p * fp8_f32<0>(hv.y); a[5] += p * fp8_f32<1>(hv.y);
        a[6] += p * fp8_f32<2>(hv.y); a[7] += p * fp8_f32<3>(hv.y);
      }
#pragma unroll
      for (int msk = 1; msk <= 8; msk <<= 1)
#pragma unroll
        for (int j = 0; j < 8; ++j) a[j] += __shfl_xor(a[j], msk);
      if (lsub == 0) {
        float* dst = &ctxpL[half * 128 + dch * 8];
#pragma unroll
        for (int j = 0; j < 8; ++j) dst[j] = a[j];
      }
    }
    __syncthreads();
    if (tid < 128) {
      float v = (ctxpL[tid] + ctxpL[128 + tid]) * invdL[0];
      ctxL[tid] = v;
      float vo = __shfl_xor(v, 1);               // pack f16 pairs for P4 A
      if (!(tid & 1)) abU[tid >> 1] = pkf16(v, vo);
    }
    __syncthreads();

    // ===== P4: gates = [ctx|h] @ [W;U] =====
    if (WBF) {
      // f16 MFMA. A rows = broadcast [ctx|h] (all 16 rows identical, use
      // row 0 of D). Per wave: 8 nt tiles (2 halves x 4) x 12 kc.
      const int q = lane >> 4;
      const char* abase = smem + OFF_AB;
#pragma unroll
      for (int half = 0; half < 2; ++half) {
        const f16x8* wb = reinterpret_cast<const f16x8*>(WUf) +
                          ((size_t)t * 64 + wv * 8 + half * 4) * 12 * 64 + lane;
        f32x4 acc0 = 0, acc1 = 0, acc2 = 0, acc3 = 0;
#pragma unroll 4
        for (int kc = 0; kc < 12; ++kc) {
          f16x8 a = *(const f16x8*)(abase + kc * 64 + q * 16);
          const f16x8* bp = wb + (size_t)kc * 64;
          acc0 = __builtin_amdgcn_mfma_f32_16x16x32_f16(a, bp[0], acc0, 0, 0, 0);
          acc1 = __builtin_amdgcn_mfma_f32_16x16x32_f16(a, bp[12 * 64], acc1, 0, 0, 0);
          acc2 = __builtin_amdgcn_mfma_f32_16x16x32_f16(a, bp[2 * 12 * 64], acc2, 0, 0, 0);
          acc3 = __builtin_amdgcn_mfma_f32_16x16x32_f16(a, bp[3 * 12 * 64], acc3, 0, 0, 0);
        }
        // D: col = nt*16 + (lane&15); row 0 (lane<16, reg 0) is the gate row
        if (lane < 16) {
          int c0 = wv * 128 + half * 64 + lane;
          gatesF[c0]      = acc0[0];
          gatesF[c0 + 16] = acc1[0];
          gatesF[c0 + 32] = acc2[0];
          gatesF[c0 + 48] = acc3[0];
        }
      }
    } else {
      // Fallback: f32 GEMV (2 d-parts).
      int gc = tid & 255, dpart = tid >> 8;
      const int c0 = gc * 4;
      float g0[4] = {0.f, 0.f, 0.f, 0.f};
      {
        const float* wpf = WF + ((size_t)(dpart * 64) * TOUT + t) * G4 + c0;
#pragma unroll 2
        for (int i4 = 0; i4 < 16; ++i4) {
          float4 cv0 = *(const float4*)&ctxL[dpart * 64 + i4 * 4];
#pragma unroll
          for (int j4 = 0; j4 < 4; ++j4) {
            float4 wf = *(const float4*)wpf;
            wpf += (size_t)TOUT * G4;
            float cc0 = (j4 == 0) ? cv0.x : (j4 == 1) ? cv0.y : (j4 == 2) ? cv0.z : cv0.w;
            g0[0] += cc0 * wf.x; g0[1] += cc0 * wf.y; g0[2] += cc0 * wf.z; g0[3] += cc0 * wf.w;
          }
        }
      }
      {
        const float* upf = UF + ((size_t)(dpart * 128) * TOUT + t) * G4 + c0;
#pragma unroll 2
        for (int i4 = 0; i4 < 32; ++i4) {
          float4 hv0 = *(const float4*)&hL[dpart * 128 + i4 * 4];
#pragma unroll
          for (int j4 = 0; j4 < 4; ++j4) {
            float4 wf = *(const float4*)upf;
            upf += (size_t)TOUT * G4;
            float hh0 = (j4 == 0) ? hv0.x : (j4 == 1) ? hv0.y : (j4 == 2) ? hv0.z : hv0.w;
            g0[0] += hh0 * wf.x; g0[1] += hh0 * wf.y; g0[2] += hh0 * wf.z; g0[3] += hh0 * wf.w;
          }
        }
      }
      *(uint2*)&gatepU[dpart * 512 + gc * 2] =
          make_uint2(pkbf(g0[0], g0[1]), pkbf(g0[2], g0[3]));
    }
    __syncthreads();

    // ===== P5: LSTM cell + y =====
    float ypart = 0.f;
    if (tid < 256) {
      float yprev = yL[0];
      float gv[4];
#pragma unroll
      for (int gi = 0; gi < 4; ++gi) {
        int col = gi * 256 + tid;
        float s;
        if (WBF) {
          s = gatesF[col];
        } else {
          int ci = col >> 1, sel = col & 1;
          s = 0.f;
#pragma unroll
          for (int p = 0; p < 2; ++p) {
            u32 u = gatepU[p * 512 + ci];
            s += sel ? bfhi(u) : bflo(u);
          }
        }
        s += bias[(size_t)t * G4 + col];
        gv[gi] = s + yprev * WyF[t * G4 + col];
      }
      float ig = sigmoid_acc(gv[0]);
      float fg = sigmoid_acc(gv[1]);
      float gg = tanh_acc(gv[2]);
      float og = sigmoid_acc(gv[3]);
      float cn = fg * cL[tid] + ig * gg;
      float hn = og * tanh_acc(cn);
      cL[tid] = cn;
      hL[tid] = hn;
      out[12288 + ((size_t)bg * TOUT + t) * HS + tid] = hn;
      ypart = hn * fcw[t * HS + tid];
      float hho = __shfl_xor(hn, 1);             // pack f16 pairs for next P4
      if (!(tid & 1)) abU[64 + (tid >> 1)] = pkf16(hn, hho);
    }
#pragma unroll
    for (int msk = 1; msk <= 32; msk <<= 1) ypart += __shfl_xor(ypart, msk);
    if (tid < 256 && lane == 0) redL[16 + wv] = ypart;   // wv 0..3 here
    __syncthreads();
    if (tid == 0) {
      float y = redL[16] + redL[17] + redL[18] + redL[19] + fcb[t];
      yL[0] = y;
      out[(size_t)bg * TOUT + t] = y;
    }
    __syncthreads();
  }
}

extern "C" void kernel_launch(void* const* d_in, const int* in_sizes, int n_in, void* d_out,
                              int out_size, void* d_ws, size_t ws_size, hipStream_t stream) {
  const float* H    = (const float*)d_in[0];
  const float* y0   = (const float*)d_in[1];
  const float* emb  = (const float*)d_in[2];
  const float* Wa   = (const float*)d_in[3];
  const float* Ua   = (const float*)d_in[4];
  const float* ba   = (const float*)d_in[5];
  const float* Va   = (const float*)d_in[6];
  const float* W    = (const float*)d_in[7];
  const float* U    = (const float*)d_in[8];
  const float* bias = (const float*)d_in[9];
  const float* Wy   = (const float*)d_in[10];
  const float* fcw  = (const float*)d_in[11];
  const float* fcb  = (const float*)d_in[12];
  float* out = (float*)d_out;

  const size_t nFrag = (size_t)TOUT * 64 * 12 * 64;   // 1,179,648 frags x 16B
  const size_t need = nFrag * 16;                     // 18,874,368 B
  const bool usebf = (d_ws != nullptr) && (ws_size >= need);
  u32* WUf = (u32*)d_ws;

  if (usebf) {
    repack_f16_kernel<<<(int)(nFrag / 256), 256, 0, stream>>>(W, U, WUf);
  }

  hipFuncSetAttribute((const void*)lstm_attn_kernel<1>,
                      hipFuncAttributeMaxDynamicSharedMemorySize, SMEM_BYTES);
  hipFuncSetAttribute((const void*)lstm_attn_kernel<0>,
                      hipFuncAttributeMaxDynamicSharedMemorySize, SMEM_BYTES);

  if (usebf) {
    lstm_attn_kernel<1><<<NB, 512, SMEM_BYTES, stream>>>(
        H, y0, emb, Wa, Ua, ba, Va, W, U, bias, Wy, fcw, fcb, WUf, out);
  } else {
    lstm_attn_kernel<0><<<NB, 512, SMEM_BYTES, stream>>>(
        H, y0, emb, Wa, Ua, ba, Va, W, U, bias, Wy, fcw, fcb, WUf, out);
  }
}